// Round 1
// baseline (3999.885 us; speedup 1.0000x reference)
//
#include <hip/hip_runtime.h>
#include <stdint.h>

typedef unsigned int uint;
typedef unsigned short ushort;

__device__ __forceinline__ uint f2bf(float f) {
  uint u = __float_as_uint(f);
  return (u + 0x7fffu + ((u >> 16) & 1u)) >> 16;
}
__device__ __forceinline__ float bf2f(uint us) {
  return __uint_as_float(us << 16);
}

// ---------------- weight preprocessing ----------------
// w1: (256, 128, 1, 11)  w2: (256, 128, 1, 40)
// w1nt[d][t][c] = w1[c][64+d][t]           (64*11*256)
// U1t[d][c]     = sum_t (w1[c][d][t] - w1[c][64+d][t])
// w2nt[d][j][c] = w2[c][64+d][j]           (64*20*256)
// w2it[ci][j][c]= w2[c][ci][20+j]          (128*20*256)
// U2t[d][c]     = sum_j (w2[c][d][j] - w2[c][64+d][j])
__global__ __launch_bounds__(256) void prep_weights(
    const float* __restrict__ w1, const float* __restrict__ w2,
    float* __restrict__ w1nt, float* __restrict__ U1t,
    float* __restrict__ w2nt, float* __restrict__ w2it, float* __restrict__ U2t) {
  int g = blockIdx.x * 256 + threadIdx.x;
  if (g < 180224) {
    int d = g / 2816;
    int r = g - d * 2816;
    int t = r >> 8, c = r & 255;
    w1nt[g] = w1[c * 1408 + (64 + d) * 11 + t];
  } else if (g < 196608) {
    int q = g - 180224; int d = q >> 8, c = q & 255;
    float s = 0.f;
    for (int t = 0; t < 11; ++t)
      s += w1[c * 1408 + d * 11 + t] - w1[c * 1408 + (64 + d) * 11 + t];
    U1t[q] = s;
  } else if (g < 524288) {
    int q = g - 196608;
    int d = q / 5120; int r = q - d * 5120; int j = r >> 8, c = r & 255;
    w2nt[q] = w2[c * 5120 + (64 + d) * 40 + j];
  } else if (g < 1179648) {
    int q = g - 524288;
    int ci = q / 5120; int r = q - ci * 5120; int j = r >> 8, c = r & 255;
    w2it[q] = w2[c * 5120 + ci * 40 + 20 + j];
  } else if (g < 1196032) {
    int q = g - 1179648; int d = q >> 8, c = q & 255;
    float s = 0.f;
    for (int j = 0; j < 20; ++j)
      s += w2[c * 5120 + d * 40 + j] - w2[c * 5120 + (64 + d) * 40 + j];
    U2t[q] = s;
  }
}

// ---------------- squared norms (fp64) ----------------
__global__ __launch_bounds__(256) void sqnorm_kernel(const float* __restrict__ x,
                                                     double* __restrict__ sqd) {
  int g = blockIdx.x * 256 + threadIdx.x;  // 16384
  int b = g >> 11, n = g & 2047;
  const float* xp = x + b * 131072 + n;
  double s = 0.0;
  #pragma unroll
  for (int d = 0; d < 64; ++d) { double v = (double)xp[d * 2048]; s += v * v; }
  sqd[g] = s;
}

// ---------------- kNN: 4 rows/block, fp64 dists, stable top-21 ----------------
__global__ __launch_bounds__(256) void knn_kernel(const float* __restrict__ x,
                                                  const double* __restrict__ sqd,
                                                  int* __restrict__ idxout) {
  __shared__ double xi[4][64];
  __shared__ double dist[4][2048];
  int tid = threadIdx.x;
  int row0 = blockIdx.x << 2;
  int b = row0 >> 11, n0 = row0 & 2047;
  { int r = tid >> 6, d = tid & 63; xi[r][d] = (double)x[b * 131072 + d * 2048 + n0 + r]; }
  __syncthreads();
  double sqi0 = sqd[row0], sqi1 = sqd[row0 + 1], sqi2 = sqd[row0 + 2], sqi3 = sqd[row0 + 3];
  const float* xb = x + b * 131072;
  for (int jj = 0; jj < 8; ++jj) {
    int j = (jj << 8) + tid;
    double a0 = 0, a1 = 0, a2 = 0, a3 = 0;
    #pragma unroll
    for (int d = 0; d < 64; ++d) {
      double v = (double)xb[d * 2048 + j];
      a0 += xi[0][d] * v; a1 += xi[1][d] * v; a2 += xi[2][d] * v; a3 += xi[3][d] * v;
    }
    double sqj = sqd[b * 2048 + j];
    dist[0][j] = sqi0 + sqj - 2.0 * a0;
    dist[1][j] = sqi1 + sqj - 2.0 * a1;
    dist[2][j] = sqi2 + sqj - 2.0 * a2;
    dist[3][j] = sqi3 + sqj - 2.0 * a3;
  }
  __syncthreads();
  // one wave per row; iterative argmin with (val, idx) lexicographic order
  int wv = tid >> 6, lane = tid & 63;
  double* dr = dist[wv];
  double lv = 1e300; int li = 0x7fffffff;
  for (int l = 0; l < 32; ++l) {
    int jdx = (l << 6) + lane;
    double v = dr[jdx];
    if (v < lv) { lv = v; li = jdx; }
  }
  int outbase = (row0 + wv) * 20;
  for (int pick = 0; pick <= 20; ++pick) {
    double bv = lv; int bi = li;
    #pragma unroll
    for (int off = 32; off > 0; off >>= 1) {
      double ov = __shfl_xor(bv, off);
      int oi = __shfl_xor(bi, off);
      if (ov < bv || (ov == bv && oi < bi)) { bv = ov; bi = oi; }
    }
    if (pick > 0 && lane == 0) idxout[outbase + pick - 1] = bi;  // pick 0 == self
    if ((bi & 63) == lane) {
      dr[bi] = 1e300;
      lv = 1e300; li = 0x7fffffff;
      for (int l = 0; l < 32; ++l) {
        int jdx = (l << 6) + lane;
        double v = dr[jdx];
        if (v < lv) { lv = v; li = jdx; }
      }
    }
  }
}

// ---------------- conv1 (central-collapsed) -> h (bf16) ----------------
// h layout: [row=b*2048+n][c(256)][ko(10)] as bf16 pairs in uint
__global__ __launch_bounds__(256) void conv1_kernel(
    const float* __restrict__ x, const int* __restrict__ idxbuf,
    const float* __restrict__ w1nt, const float* __restrict__ U1t,
    uint* __restrict__ hu) {
  __shared__ float cen[4][64];
  __shared__ float nb[4][64][20];
  __shared__ int nidx[4][20];
  int tid = threadIdx.x;
  int p0 = blockIdx.x << 2;
  int b = p0 >> 11, n0 = p0 & 2047;
  if (tid < 80) { int p = tid / 20, j = tid - p * 20; nidx[p][j] = idxbuf[(p0 + p) * 20 + j]; }
  { int p = tid >> 6, d = tid & 63; cen[p][d] = x[b * 131072 + d * 2048 + n0 + p]; }
  __syncthreads();
  const float* xb = x + b * 131072;
  #pragma unroll
  for (int it = 0; it < 20; ++it) {
    int f = (it << 8) + tid;
    int p = f / 1280; int r = f - p * 1280; int d = r / 20; int j = r - d * 20;
    nb[p][d][j] = xb[d * 2048 + nidx[p][j]];
  }
  __syncthreads();
  int c = tid;
  float acc[4][10];
  #pragma unroll
  for (int p = 0; p < 4; ++p)
    #pragma unroll
    for (int ko = 0; ko < 10; ++ko) acc[p][ko] = 0.f;
  float ca[4] = {0.f, 0.f, 0.f, 0.f};
  for (int d = 0; d < 64; ++d) {
    float u = U1t[(d << 8) + c];
    float w[11];
    #pragma unroll
    for (int t = 0; t < 11; ++t) w[t] = w1nt[(d * 11 + t) * 256 + c];
    #pragma unroll
    for (int p = 0; p < 4; ++p) {
      ca[p] += cen[p][d] * u;
      float e[20];
      #pragma unroll
      for (int q = 0; q < 20; ++q) e[q] = nb[p][d][q];
      #pragma unroll
      for (int ko = 0; ko < 10; ++ko) {
        float s = acc[p][ko];
        #pragma unroll
        for (int t = 0; t < 11; ++t) s += w[t] * e[ko + t];
        acc[p][ko] = s;
      }
    }
  }
  #pragma unroll
  for (int p = 0; p < 4; ++p) {
    int base5 = ((p0 + p) * 256 + c) * 5;
    #pragma unroll
    for (int q = 0; q < 5; ++q) {
      float f0 = acc[p][2 * q] + ca[p];
      float f1 = acc[p][2 * q + 1] + ca[p];
      hu[base5 + q] = f2bf(f0) | (f2bf(f1) << 16);
    }
  }
}

// ---------------- BN stats ----------------
__global__ __launch_bounds__(256) void stats1_kernel(const uint* __restrict__ hu,
                                                     float* __restrict__ stats) {
  int c = threadIdx.x;
  float s = 0.f, ss = 0.f;
  for (int row = blockIdx.x; row < 16384; row += 128) {
    int base = (row * 256 + c) * 5;
    #pragma unroll
    for (int q = 0; q < 5; ++q) {
      uint v = hu[base + q];
      float f0 = bf2f(v & 0xffffu), f1 = bf2f(v >> 16);
      s += f0 + f1; ss += f0 * f0 + f1 * f1;
    }
  }
  atomicAdd(&stats[c], s);
  atomicAdd(&stats[256 + c], ss);
}

__global__ void finalize_kernel(const float* __restrict__ stats,
                                const float* __restrict__ gamma,
                                const float* __restrict__ beta,
                                float* __restrict__ coef, float inv_count) {
  int c = threadIdx.x;
  float m = stats[c] * inv_count;
  float var = stats[256 + c] * inv_count - m * m;
  float a = gamma[c] * rsqrtf(var + 1e-5f);
  coef[c] = a;
  coef[256 + c] = beta[c] - m * a;
}

// ---------------- conv2 (central-collapsed, 2ch x 2pt per thread) ----------------
__global__ __launch_bounds__(256) void conv2_kernel(
    const float* __restrict__ x, const int* __restrict__ idxbuf,
    const uint* __restrict__ hu, const float* __restrict__ coef1,
    const float* __restrict__ w2nt, const float* __restrict__ w2it,
    const float* __restrict__ U2t, float* __restrict__ yraw) {
  __shared__ float cen[4][64];
  __shared__ float nb[4][64][20];
  __shared__ float th[4][2560];
  __shared__ int nidx[4][20];
  int tid = threadIdx.x;
  int p0 = blockIdx.x << 2;
  int b = p0 >> 11, n0 = p0 & 2047;
  if (tid < 80) { int p = tid / 20, j = tid - p * 20; nidx[p][j] = idxbuf[(p0 + p) * 20 + j]; }
  { int p = tid >> 6, d = tid & 63; cen[p][d] = x[b * 131072 + d * 2048 + n0 + p]; }
  __syncthreads();
  const float* xb = x + b * 131072;
  #pragma unroll
  for (int it = 0; it < 20; ++it) {
    int f = (it << 8) + tid;
    int p = f / 1280; int r = f - p * 1280; int d = r / 20; int j = r - d * 20;
    nb[p][d][j] = xb[d * 2048 + nidx[p][j]];
  }
  // transformed h: th[p][ci*20+j] == inte value (BN1 + leaky applied)
  #pragma unroll
  for (int it = 0; it < 20; ++it) {
    int f = (it << 8) + tid;
    int p = f / 1280; int q = f - p * 1280;
    uint v = hu[(p0 + p) * 1280 + q];
    int ch = q / 5;
    float av = coef1[ch], bv = coef1[256 + ch];
    float f0 = bf2f(v & 0xffffu) * av + bv;
    float f1 = bf2f(v >> 16) * av + bv;
    f0 = f0 > 0.f ? f0 : 0.01f * f0;
    f1 = f1 > 0.f ? f1 : 0.01f * f1;
    th[p][2 * q] = f0; th[p][2 * q + 1] = f1;
  }
  __syncthreads();
  int cl = tid & 127, half = tid >> 7;
  int c0 = cl, c1 = cl + 128;
  float acc0[2] = {0.f, 0.f}, acc1[2] = {0.f, 0.f};
  for (int d = 0; d < 64; ++d) {
    float u0 = U2t[(d << 8) + c0], u1 = U2t[(d << 8) + c1];
    float wn0[20], wn1[20];
    #pragma unroll
    for (int j = 0; j < 20; ++j) {
      wn0[j] = w2nt[(d * 20 + j) * 256 + c0];
      wn1[j] = w2nt[(d * 20 + j) * 256 + c1];
    }
    #pragma unroll
    for (int pl = 0; pl < 2; ++pl) {
      int p = half * 2 + pl;
      float cv = cen[p][d];
      float s0 = acc0[pl] + cv * u0;
      float s1 = acc1[pl] + cv * u1;
      float e[20];
      #pragma unroll
      for (int q = 0; q < 20; ++q) e[q] = nb[p][d][q];
      #pragma unroll
      for (int j = 0; j < 20; ++j) { s0 += wn0[j] * e[j]; s1 += wn1[j] * e[j]; }
      acc0[pl] = s0; acc1[pl] = s1;
    }
  }
  for (int ci = 0; ci < 128; ++ci) {
    float wi0[20], wi1[20];
    #pragma unroll
    for (int j = 0; j < 20; ++j) {
      wi0[j] = w2it[(ci * 20 + j) * 256 + c0];
      wi1[j] = w2it[(ci * 20 + j) * 256 + c1];
    }
    #pragma unroll
    for (int pl = 0; pl < 2; ++pl) {
      int p = half * 2 + pl;
      const float* tp = &th[p][ci * 20];
      float s0 = acc0[pl], s1 = acc1[pl];
      #pragma unroll
      for (int j = 0; j < 20; ++j) { float v = tp[j]; s0 += wi0[j] * v; s1 += wi1[j] * v; }
      acc0[pl] = s0; acc1[pl] = s1;
    }
  }
  #pragma unroll
  for (int pl = 0; pl < 2; ++pl) {
    int p = half * 2 + pl;
    yraw[(p0 + p) * 256 + c0] = acc0[pl];
    yraw[(p0 + p) * 256 + c1] = acc1[pl];
  }
}

__global__ __launch_bounds__(256) void stats2_kernel(const float* __restrict__ yraw,
                                                     float* __restrict__ stats) {
  int c = threadIdx.x;
  float s = 0.f, ss = 0.f;
  for (int row = blockIdx.x; row < 16384; row += 128) {
    float v = yraw[row * 256 + c];
    s += v; ss += v * v;
  }
  atomicAdd(&stats[c], s);
  atomicAdd(&stats[256 + c], ss);
}

// ---------------- BN2 + relu + transpose to (b, c, n) ----------------
__global__ __launch_bounds__(256) void out_kernel(const float* __restrict__ yraw,
                                                  const float* __restrict__ coef2,
                                                  float* __restrict__ out) {
  __shared__ float t[64][257];
  int tid = threadIdx.x;
  int blk = blockIdx.x;            // 256 = 8 b x 32 n-tiles
  int b = blk >> 5, n0 = (blk & 31) << 6;
  for (int it = 0; it < 64; ++it)
    t[it][tid] = yraw[(b * 2048 + n0 + it) * 256 + tid];
  __syncthreads();
  int nsub = tid & 63, cq = tid >> 6;
  for (int it = 0; it < 64; ++it) {
    int c = (it << 2) + cq;
    float v = coef2[c] * t[nsub][c] + coef2[256 + c];
    out[(b * 256 + c) * 2048 + n0 + nsub] = v > 0.f ? v : 0.f;
  }
}

extern "C" void kernel_launch(void* const* d_in, const int* in_sizes, int n_in,
                              void* d_out, int out_size, void* d_ws, size_t ws_size,
                              hipStream_t stream) {
  const float* x   = (const float*)d_in[0];
  const float* w1  = (const float*)d_in[1];
  const float* g1  = (const float*)d_in[3];
  const float* be1 = (const float*)d_in[4];
  const float* w2  = (const float*)d_in[5];
  const float* g2  = (const float*)d_in[7];
  const float* be2 = (const float*)d_in[8];
  float* out = (float*)d_out;
  char* w = (char*)d_ws;
  // workspace layout (102 MB total)
  double* sqd  = (double*)(w);                 // 16384 * 8      = 131072
  int*  idxbuf = (int*)(w + 131072);           // 327680 * 4     = 1310720
  uint* hu     = (uint*)(w + 1441792);         // h bf16: 41.94M*2 = 83886080
  float* yraw  = (float*)(w + 85327872);       // 4194304 * 4    = 16777216
  float* stats = (float*)(w + 102105088);      // 4 * 256 floats
  float* coef  = (float*)(w + 102109184);      // 4 * 256 floats
  float* w1nt  = (float*)(w + 102113280);      // 180224 * 4
  float* U1t   = (float*)(w + 102834176);      // 16384 * 4
  float* w2nt  = (float*)(w + 102899712);      // 327680 * 4
  float* w2it  = (float*)(w + 104210432);      // 655360 * 4
  float* U2t   = (float*)(w + 106831872);      // 16384 * 4 -> end 106897408

  hipMemsetAsync(stats, 0, 4096, stream);
  prep_weights<<<4672, 256, 0, stream>>>(w1, w2, w1nt, U1t, w2nt, w2it, U2t);
  sqnorm_kernel<<<64, 256, 0, stream>>>(x, sqd);
  knn_kernel<<<4096, 256, 0, stream>>>(x, sqd, idxbuf);
  conv1_kernel<<<4096, 256, 0, stream>>>(x, idxbuf, w1nt, U1t, hu);
  stats1_kernel<<<128, 256, 0, stream>>>(hu, stats);
  finalize_kernel<<<1, 256, 0, stream>>>(stats, g1, be1, coef, 1.f / 163840.f);
  conv2_kernel<<<4096, 256, 0, stream>>>(x, idxbuf, hu, coef, w2nt, w2it, U2t, yraw);
  stats2_kernel<<<128, 256, 0, stream>>>(yraw, stats + 512);
  finalize_kernel<<<1, 256, 0, stream>>>(stats + 512, g2, be2, coef + 512, 1.f / 16384.f);
  out_kernel<<<256, 256, 0, stream>>>(yraw, coef + 512, out);
}

// Round 3
// 3528.389 us; speedup vs baseline: 1.1336x; 1.1336x over previous
//
#include <hip/hip_runtime.h>
#include <stdint.h>

typedef unsigned int uint;
typedef unsigned short ushort;

__device__ __forceinline__ uint f2bf(float f) {
  uint u = __float_as_uint(f);
  return (u + 0x7fffu + ((u >> 16) & 1u)) >> 16;
}
__device__ __forceinline__ float bf2f(uint us) {
  return __uint_as_float(us << 16);
}

// ---------------- weight preprocessing ----------------
// w1: (256, 128, 1, 11)  w2: (256, 128, 1, 40)
// w1nt[d][t][c] = w1[c][64+d][t]           (64*11*256)
// U1t[d][c]     = sum_t (w1[c][d][t] - w1[c][64+d][t])
// w2nt[d][j][c] = w2[c][64+d][j]           (64*20*256)
// w2it[ci][j][c]= w2[c][ci][20+j]          (128*20*256)
// U2t[d][c]     = sum_j (w2[c][d][j] - w2[c][64+d][j])
__global__ __launch_bounds__(256) void prep_weights(
    const float* __restrict__ w1, const float* __restrict__ w2,
    float* __restrict__ w1nt, float* __restrict__ U1t,
    float* __restrict__ w2nt, float* __restrict__ w2it, float* __restrict__ U2t) {
  int g = blockIdx.x * 256 + threadIdx.x;
  if (g < 180224) {
    int d = g / 2816;
    int r = g - d * 2816;
    int t = r >> 8, c = r & 255;
    w1nt[g] = w1[c * 1408 + (64 + d) * 11 + t];
  } else if (g < 196608) {
    int q = g - 180224; int d = q >> 8, c = q & 255;
    float s = 0.f;
    for (int t = 0; t < 11; ++t)
      s += w1[c * 1408 + d * 11 + t] - w1[c * 1408 + (64 + d) * 11 + t];
    U1t[q] = s;
  } else if (g < 524288) {
    int q = g - 196608;
    int d = q / 5120; int r = q - d * 5120; int j = r >> 8, c = r & 255;
    w2nt[q] = w2[c * 5120 + (64 + d) * 40 + j];
  } else if (g < 1179648) {
    int q = g - 524288;
    int ci = q / 5120; int r = q - ci * 5120; int j = r >> 8, c = r & 255;
    w2it[q] = w2[c * 5120 + ci * 40 + 20 + j];
  } else if (g < 1196032) {
    int q = g - 1179648; int d = q >> 8, c = q & 255;
    float s = 0.f;
    for (int j = 0; j < 20; ++j)
      s += w2[c * 5120 + d * 40 + j] - w2[c * 5120 + (64 + d) * 40 + j];
    U2t[q] = s;
  }
}

// ---------------- squared norms (fp32, for the fp32 pre-selection only) ----------------
__global__ __launch_bounds__(256) void sqnorm_kernel(const float* __restrict__ x,
                                                     float* __restrict__ sqf) {
  int g = blockIdx.x * 256 + threadIdx.x;  // 16384
  int b = g >> 11, n = g & 2047;
  const float* xp = x + b * 131072 + n;
  float s = 0.f;
  #pragma unroll
  for (int d = 0; d < 64; ++d) { float v = xp[d * 2048]; s += v * v; }
  sqf[g] = s;
}

// ---------------- kNN v3: fp32 top-28 superset, fp64 exact re-rank ----------------
// Phase 1: fp32 keys key_j = sq_j - 2*dot (sq_i constant per row -> dropped).
// Phase 2: wave-per-row register-resident selection of 28 smallest (pick 0 is
//          provably self: margin = nearest-neighbor dist² >> fp32 noise).
// Phase 3: fp64 exact keys for the 27 non-self candidates; rank by (key, idx);
//          ranks 0..19 are the output neighbors. fp64 products of fp32 inputs
//          are exact, so this reproduces a float64 reference's ordering.
__global__ __launch_bounds__(256) void knn_kernel(const float* __restrict__ x,
                                                  const float* __restrict__ sqf,
                                                  int* __restrict__ idxout) {
  __shared__ float xi[4][64];
  __shared__ float dist[4][2048];   // 32 KB
  __shared__ int cand[4][27];
  __shared__ double dkey[4][27];
  int tid = threadIdx.x;
  int row0 = blockIdx.x << 2;
  int b = row0 >> 11, n0 = row0 & 2047;
  { int r = tid >> 6, d = tid & 63; xi[r][d] = x[b * 131072 + d * 2048 + n0 + r]; }
  __syncthreads();
  const float* xb = x + b * 131072;
  const float* sqb = sqf + b * 2048;
  for (int jj = 0; jj < 8; ++jj) {
    int j = (jj << 8) + tid;
    float a0 = 0.f, a1 = 0.f, a2 = 0.f, a3 = 0.f;
    #pragma unroll
    for (int d = 0; d < 64; ++d) {
      float v = xb[d * 2048 + j];
      a0 += xi[0][d] * v; a1 += xi[1][d] * v; a2 += xi[2][d] * v; a3 += xi[3][d] * v;
    }
    float sqj = sqb[j];
    dist[0][j] = sqj - 2.f * a0;
    dist[1][j] = sqj - 2.f * a1;
    dist[2][j] = sqj - 2.f * a2;
    dist[3][j] = sqj - 2.f * a3;
  }
  __syncthreads();
  // ---- phase 2: one wave per row; dists in 32 regs/lane; col j = (l<<6)+lane
  int wv = tid >> 6, lane = tid & 63;
  const float* dr = dist[wv];
  float v[32];
  #pragma unroll
  for (int l = 0; l < 32; ++l) v[l] = dr[(l << 6) + lane];
  for (int pick = 0; pick < 28; ++pick) {
    float bv = v[0]; int bl = 0;
    #pragma unroll
    for (int l = 1; l < 32; ++l) { if (v[l] < bv) { bv = v[l]; bl = l; } }
    int bj = (bl << 6) + lane;
    #pragma unroll
    for (int off = 32; off > 0; off >>= 1) {
      float ov = __shfl_xor(bv, off);
      int oj = __shfl_xor(bj, off);
      if (ov < bv || (ov == bv && oj < bj)) { bv = ov; bj = oj; }
    }
    if (pick > 0 && lane == 0) cand[wv][pick - 1] = bj;  // pick 0 == self
    int kill = ((bj & 63) == lane) ? (bj >> 6) : 32;
    #pragma unroll
    for (int l = 0; l < 32; ++l) { if (l == kill) v[l] = 3e38f; }
  }
  __syncthreads();
  // ---- phase 3: fp64 exact keys for 27 candidates, rank, emit top-20
  if (lane < 27) {
    int c = cand[wv][lane];
    double dt = 0.0, s2 = 0.0;
    #pragma unroll 8
    for (int d = 0; d < 64; ++d) {
      double vv = (double)xb[d * 2048 + c];
      s2 += vv * vv;
      dt += (double)xi[wv][d] * vv;
    }
    dkey[wv][lane] = s2 - 2.0 * dt;
  }
  __syncthreads();
  if (lane < 27) {
    double kl = dkey[wv][lane];
    int ci = cand[wv][lane];
    int rank = 0;
    for (int m = 0; m < 27; ++m) {
      double km = dkey[wv][m];
      int cm = cand[wv][m];
      if (km < kl || (km == kl && cm < ci)) ++rank;
    }
    if (rank < 20) idxout[(row0 + wv) * 20 + rank] = ci;
  }
}

// ---------------- conv1 (central-collapsed) -> h (bf16) ----------------
// h layout: [row=b*2048+n][c(256)][ko(10)] as bf16 pairs in uint
__global__ __launch_bounds__(256) void conv1_kernel(
    const float* __restrict__ x, const int* __restrict__ idxbuf,
    const float* __restrict__ w1nt, const float* __restrict__ U1t,
    uint* __restrict__ hu) {
  __shared__ float cen[4][64];
  __shared__ float nb[4][64][20];
  __shared__ int nidx[4][20];
  int tid = threadIdx.x;
  int p0 = blockIdx.x << 2;
  int b = p0 >> 11, n0 = p0 & 2047;
  if (tid < 80) { int p = tid / 20, j = tid - p * 20; nidx[p][j] = idxbuf[(p0 + p) * 20 + j]; }
  { int p = tid >> 6, d = tid & 63; cen[p][d] = x[b * 131072 + d * 2048 + n0 + p]; }
  __syncthreads();
  const float* xb = x + b * 131072;
  #pragma unroll
  for (int it = 0; it < 20; ++it) {
    int f = (it << 8) + tid;
    int p = f / 1280; int r = f - p * 1280; int d = r / 20; int j = r - d * 20;
    nb[p][d][j] = xb[d * 2048 + nidx[p][j]];
  }
  __syncthreads();
  int c = tid;
  float acc[4][10];
  #pragma unroll
  for (int p = 0; p < 4; ++p)
    #pragma unroll
    for (int ko = 0; ko < 10; ++ko) acc[p][ko] = 0.f;
  float ca[4] = {0.f, 0.f, 0.f, 0.f};
  for (int d = 0; d < 64; ++d) {
    float u = U1t[(d << 8) + c];
    float w[11];
    #pragma unroll
    for (int t = 0; t < 11; ++t) w[t] = w1nt[(d * 11 + t) * 256 + c];
    #pragma unroll
    for (int p = 0; p < 4; ++p) {
      ca[p] += cen[p][d] * u;
      float e[20];
      #pragma unroll
      for (int q = 0; q < 20; ++q) e[q] = nb[p][d][q];
      #pragma unroll
      for (int ko = 0; ko < 10; ++ko) {
        float s = acc[p][ko];
        #pragma unroll
        for (int t = 0; t < 11; ++t) s += w[t] * e[ko + t];
        acc[p][ko] = s;
      }
    }
  }
  #pragma unroll
  for (int p = 0; p < 4; ++p) {
    int base5 = ((p0 + p) * 256 + c) * 5;
    #pragma unroll
    for (int q = 0; q < 5; ++q) {
      float f0 = acc[p][2 * q] + ca[p];
      float f1 = acc[p][2 * q + 1] + ca[p];
      hu[base5 + q] = f2bf(f0) | (f2bf(f1) << 16);
    }
  }
}

// ---------------- BN stats ----------------
__global__ __launch_bounds__(256) void stats1_kernel(const uint* __restrict__ hu,
                                                     float* __restrict__ stats) {
  int c = threadIdx.x;
  float s = 0.f, ss = 0.f;
  for (int row = blockIdx.x; row < 16384; row += 128) {
    int base = (row * 256 + c) * 5;
    #pragma unroll
    for (int q = 0; q < 5; ++q) {
      uint v = hu[base + q];
      float f0 = bf2f(v & 0xffffu), f1 = bf2f(v >> 16);
      s += f0 + f1; ss += f0 * f0 + f1 * f1;
    }
  }
  atomicAdd(&stats[c], s);
  atomicAdd(&stats[256 + c], ss);
}

__global__ void finalize_kernel(const float* __restrict__ stats,
                                const float* __restrict__ gamma,
                                const float* __restrict__ beta,
                                float* __restrict__ coef, float inv_count) {
  int c = threadIdx.x;
  float m = stats[c] * inv_count;
  float var = stats[256 + c] * inv_count - m * m;
  float a = gamma[c] * rsqrtf(var + 1e-5f);
  coef[c] = a;
  coef[256 + c] = beta[c] - m * a;
}

// ---------------- conv2 (central-collapsed, 2ch x 2pt per thread) ----------------
__global__ __launch_bounds__(256) void conv2_kernel(
    const float* __restrict__ x, const int* __restrict__ idxbuf,
    const uint* __restrict__ hu, const float* __restrict__ coef1,
    const float* __restrict__ w2nt, const float* __restrict__ w2it,
    const float* __restrict__ U2t, float* __restrict__ yraw) {
  __shared__ float cen[4][64];
  __shared__ float nb[4][64][20];
  __shared__ float th[4][2560];
  __shared__ int nidx[4][20];
  int tid = threadIdx.x;
  int p0 = blockIdx.x << 2;
  int b = p0 >> 11, n0 = p0 & 2047;
  if (tid < 80) { int p = tid / 20, j = tid - p * 20; nidx[p][j] = idxbuf[(p0 + p) * 20 + j]; }
  { int p = tid >> 6, d = tid & 63; cen[p][d] = x[b * 131072 + d * 2048 + n0 + p]; }
  __syncthreads();
  const float* xb = x + b * 131072;
  #pragma unroll
  for (int it = 0; it < 20; ++it) {
    int f = (it << 8) + tid;
    int p = f / 1280; int r = f - p * 1280; int d = r / 20; int j = r - d * 20;
    nb[p][d][j] = xb[d * 2048 + nidx[p][j]];
  }
  // transformed h: th[p][ci*20+j] == inte value (BN1 + leaky applied)
  #pragma unroll
  for (int it = 0; it < 20; ++it) {
    int f = (it << 8) + tid;
    int p = f / 1280; int q = f - p * 1280;
    uint v = hu[(p0 + p) * 1280 + q];
    int ch = q / 5;
    float av = coef1[ch], bv = coef1[256 + ch];
    float f0 = bf2f(v & 0xffffu) * av + bv;
    float f1 = bf2f(v >> 16) * av + bv;
    f0 = f0 > 0.f ? f0 : 0.01f * f0;
    f1 = f1 > 0.f ? f1 : 0.01f * f1;
    th[p][2 * q] = f0; th[p][2 * q + 1] = f1;
  }
  __syncthreads();
  int cl = tid & 127, half = tid >> 7;
  int c0 = cl, c1 = cl + 128;
  float acc0[2] = {0.f, 0.f}, acc1[2] = {0.f, 0.f};
  for (int d = 0; d < 64; ++d) {
    float u0 = U2t[(d << 8) + c0], u1 = U2t[(d << 8) + c1];
    float wn0[20], wn1[20];
    #pragma unroll
    for (int j = 0; j < 20; ++j) {
      wn0[j] = w2nt[(d * 20 + j) * 256 + c0];
      wn1[j] = w2nt[(d * 20 + j) * 256 + c1];
    }
    #pragma unroll
    for (int pl = 0; pl < 2; ++pl) {
      int p = half * 2 + pl;
      float cv = cen[p][d];
      float s0 = acc0[pl] + cv * u0;
      float s1 = acc1[pl] + cv * u1;
      float e[20];
      #pragma unroll
      for (int q = 0; q < 20; ++q) e[q] = nb[p][d][q];
      #pragma unroll
      for (int j = 0; j < 20; ++j) { s0 += wn0[j] * e[j]; s1 += wn1[j] * e[j]; }
      acc0[pl] = s0; acc1[pl] = s1;
    }
  }
  for (int ci = 0; ci < 128; ++ci) {
    float wi0[20], wi1[20];
    #pragma unroll
    for (int j = 0; j < 20; ++j) {
      wi0[j] = w2it[(ci * 20 + j) * 256 + c0];
      wi1[j] = w2it[(ci * 20 + j) * 256 + c1];
    }
    #pragma unroll
    for (int pl = 0; pl < 2; ++pl) {
      int p = half * 2 + pl;
      const float* tp = &th[p][ci * 20];
      float s0 = acc0[pl], s1 = acc1[pl];
      #pragma unroll
      for (int j = 0; j < 20; ++j) { float v = tp[j]; s0 += wi0[j] * v; s1 += wi1[j] * v; }
      acc0[pl] = s0; acc1[pl] = s1;
    }
  }
  #pragma unroll
  for (int pl = 0; pl < 2; ++pl) {
    int p = half * 2 + pl;
    yraw[(p0 + p) * 256 + c0] = acc0[pl];
    yraw[(p0 + p) * 256 + c1] = acc1[pl];
  }
}

__global__ __launch_bounds__(256) void stats2_kernel(const float* __restrict__ yraw,
                                                     float* __restrict__ stats) {
  int c = threadIdx.x;
  float s = 0.f, ss = 0.f;
  for (int row = blockIdx.x; row < 16384; row += 128) {
    float v = yraw[row * 256 + c];
    s += v; ss += v * v;
  }
  atomicAdd(&stats[c], s);
  atomicAdd(&stats[256 + c], ss);
}

// ---------------- BN2 + relu + transpose to (b, c, n) ----------------
__global__ __launch_bounds__(256) void out_kernel(const float* __restrict__ yraw,
                                                  const float* __restrict__ coef2,
                                                  float* __restrict__ out) {
  __shared__ float t[64][257];
  int tid = threadIdx.x;
  int blk = blockIdx.x;            // 256 = 8 b x 32 n-tiles
  int b = blk >> 5, n0 = (blk & 31) << 6;
  for (int it = 0; it < 64; ++it)
    t[it][tid] = yraw[(b * 2048 + n0 + it) * 256 + tid];
  __syncthreads();
  int nsub = tid & 63, cq = tid >> 6;
  for (int it = 0; it < 64; ++it) {
    int c = (it << 2) + cq;
    float v = coef2[c] * t[nsub][c] + coef2[256 + c];
    out[(b * 256 + c) * 2048 + n0 + nsub] = v > 0.f ? v : 0.f;
  }
}

extern "C" void kernel_launch(void* const* d_in, const int* in_sizes, int n_in,
                              void* d_out, int out_size, void* d_ws, size_t ws_size,
                              hipStream_t stream) {
  const float* x   = (const float*)d_in[0];
  const float* w1  = (const float*)d_in[1];
  const float* g1  = (const float*)d_in[3];
  const float* be1 = (const float*)d_in[4];
  const float* w2  = (const float*)d_in[5];
  const float* g2  = (const float*)d_in[7];
  const float* be2 = (const float*)d_in[8];
  float* out = (float*)d_out;
  char* w = (char*)d_ws;
  // workspace layout (~102 MB total)
  float* sqf   = (float*)(w);                  // 16384 * 4 (slot is 131072 B)
  int*  idxbuf = (int*)(w + 131072);           // 327680 * 4     = 1310720
  uint* hu     = (uint*)(w + 1441792);         // h bf16: 41.94M*2 = 83886080
  float* yraw  = (float*)(w + 85327872);       // 4194304 * 4    = 16777216
  float* stats = (float*)(w + 102105088);      // 4 * 256 floats
  float* coef  = (float*)(w + 102109184);      // 4 * 256 floats
  float* w1nt  = (float*)(w + 102113280);      // 180224 * 4
  float* U1t   = (float*)(w + 102834176);      // 16384 * 4
  float* w2nt  = (float*)(w + 102899712);      // 327680 * 4
  float* w2it  = (float*)(w + 104210432);      // 655360 * 4
  float* U2t   = (float*)(w + 106831872);      // 16384 * 4 -> end 106897408

  hipMemsetAsync(stats, 0, 4096, stream);
  prep_weights<<<4672, 256, 0, stream>>>(w1, w2, w1nt, U1t, w2nt, w2it, U2t);
  sqnorm_kernel<<<64, 256, 0, stream>>>(x, sqf);
  knn_kernel<<<4096, 256, 0, stream>>>(x, sqf, idxbuf);
  conv1_kernel<<<4096, 256, 0, stream>>>(x, idxbuf, w1nt, U1t, hu);
  stats1_kernel<<<128, 256, 0, stream>>>(hu, stats);
  finalize_kernel<<<1, 256, 0, stream>>>(stats, g1, be1, coef, 1.f / 163840.f);
  conv2_kernel<<<4096, 256, 0, stream>>>(x, idxbuf, hu, coef, w2nt, w2it, U2t, yraw);
  stats2_kernel<<<128, 256, 0, stream>>>(yraw, stats + 512);
  finalize_kernel<<<1, 256, 0, stream>>>(stats + 512, g2, be2, coef + 512, 1.f / 16384.f);
  out_kernel<<<256, 256, 0, stream>>>(yraw, coef + 512, out);
}

// Round 4
// 2455.501 us; speedup vs baseline: 1.6289x; 1.4369x over previous
//
#include <hip/hip_runtime.h>
#include <stdint.h>

typedef unsigned int uint;
typedef unsigned short ushort;
typedef __attribute__((ext_vector_type(8))) short short8;
typedef __attribute__((ext_vector_type(4))) float f32x4;

__device__ __forceinline__ uint f2bf(float f) {
  uint u = __float_as_uint(f);
  return (u + 0x7fffu + ((u >> 16) & 1u)) >> 16;
}
__device__ __forceinline__ float bf2f(uint us) {
  return __uint_as_float(us << 16);
}

// ---------------- weight preprocessing ----------------
// w1: (256, 128, 1, 11)  w2: (256, 128, 1, 40)
// w1nt[d][t][c] = w1[c][64+d][t]           (64*11*256)
// U1t[d][c]     = sum_t (w1[c][d][t] - w1[c][64+d][t])
// wpack: conv2 GEMM B, bf16, layout [kb(61)][c(256)][kk(64)]; K order:
//   k<64: U2[d=k][c];  64<=k<1344: w2[c][64+d][j] (q=k-64=d*20+j);
//   1344<=k<3904: w2[c][ci][20+jj] (q=k-1344=ci*20+jj)
__global__ __launch_bounds__(256) void prep_weights(
    const float* __restrict__ w1, const float* __restrict__ w2,
    float* __restrict__ w1nt, float* __restrict__ U1t,
    ushort* __restrict__ wpack) {
  int g = blockIdx.x * 256 + threadIdx.x;
  if (g < 180224) {
    int d = g / 2816;
    int r = g - d * 2816;
    int t = r >> 8, c = r & 255;
    w1nt[g] = w1[c * 1408 + (64 + d) * 11 + t];
  } else if (g < 196608) {
    int q = g - 180224; int d = q >> 8, c = q & 255;
    float s = 0.f;
    for (int t = 0; t < 11; ++t)
      s += w1[c * 1408 + d * 11 + t] - w1[c * 1408 + (64 + d) * 11 + t];
    U1t[q] = s;
  } else {
    int gp = g - 196608;            // < 999424 = 61*16384
    int kb = gp >> 14;
    int r = gp & 16383;
    int c = r >> 6, kk = r & 63;
    int k = kb * 64 + kk;
    float val;
    if (k < 64) {
      int d = k;
      float s = 0.f;
      for (int j = 0; j < 20; ++j)
        s += w2[c * 5120 + d * 40 + j] - w2[c * 5120 + (64 + d) * 40 + j];
      val = s;
    } else if (k < 1344) {
      int q = k - 64; int d = q / 20, j = q - d * 20;
      val = w2[c * 5120 + (64 + d) * 40 + j];
    } else {
      int q = k - 1344; int ci = q / 20, jj = q - ci * 20;
      val = w2[c * 5120 + ci * 40 + 20 + jj];
    }
    wpack[gp] = (ushort)f2bf(val);
  }
}

// ---------------- squared norms (fp32, for the fp32 pre-selection only) ----------------
__global__ __launch_bounds__(256) void sqnorm_kernel(const float* __restrict__ x,
                                                     float* __restrict__ sqf) {
  int g = blockIdx.x * 256 + threadIdx.x;  // 16384
  int b = g >> 11, n = g & 2047;
  const float* xp = x + b * 131072 + n;
  float s = 0.f;
  #pragma unroll
  for (int d = 0; d < 64; ++d) { float v = xp[d * 2048]; s += v * v; }
  sqf[g] = s;
}

// ---------------- kNN v3: fp32 top-28 superset, fp64 exact re-rank ----------------
__global__ __launch_bounds__(256) void knn_kernel(const float* __restrict__ x,
                                                  const float* __restrict__ sqf,
                                                  int* __restrict__ idxout) {
  __shared__ float xi[4][64];
  __shared__ float dist[4][2048];   // 32 KB
  __shared__ int cand[4][27];
  __shared__ double dkey[4][27];
  int tid = threadIdx.x;
  int row0 = blockIdx.x << 2;
  int b = row0 >> 11, n0 = row0 & 2047;
  { int r = tid >> 6, d = tid & 63; xi[r][d] = x[b * 131072 + d * 2048 + n0 + r]; }
  __syncthreads();
  const float* xb = x + b * 131072;
  const float* sqb = sqf + b * 2048;
  for (int jj = 0; jj < 8; ++jj) {
    int j = (jj << 8) + tid;
    float a0 = 0.f, a1 = 0.f, a2 = 0.f, a3 = 0.f;
    #pragma unroll
    for (int d = 0; d < 64; ++d) {
      float v = xb[d * 2048 + j];
      a0 += xi[0][d] * v; a1 += xi[1][d] * v; a2 += xi[2][d] * v; a3 += xi[3][d] * v;
    }
    float sqj = sqb[j];
    dist[0][j] = sqj - 2.f * a0;
    dist[1][j] = sqj - 2.f * a1;
    dist[2][j] = sqj - 2.f * a2;
    dist[3][j] = sqj - 2.f * a3;
  }
  __syncthreads();
  int wv = tid >> 6, lane = tid & 63;
  const float* dr = dist[wv];
  float v[32];
  #pragma unroll
  for (int l = 0; l < 32; ++l) v[l] = dr[(l << 6) + lane];
  for (int pick = 0; pick < 28; ++pick) {
    float bv = v[0]; int bl = 0;
    #pragma unroll
    for (int l = 1; l < 32; ++l) { if (v[l] < bv) { bv = v[l]; bl = l; } }
    int bj = (bl << 6) + lane;
    #pragma unroll
    for (int off = 32; off > 0; off >>= 1) {
      float ov = __shfl_xor(bv, off);
      int oj = __shfl_xor(bj, off);
      if (ov < bv || (ov == bv && oj < bj)) { bv = ov; bj = oj; }
    }
    if (pick > 0 && lane == 0) cand[wv][pick - 1] = bj;  // pick 0 == self
    int kill = ((bj & 63) == lane) ? (bj >> 6) : 32;
    #pragma unroll
    for (int l = 0; l < 32; ++l) { if (l == kill) v[l] = 3e38f; }
  }
  __syncthreads();
  if (lane < 27) {
    int c = cand[wv][lane];
    double dt = 0.0, s2 = 0.0;
    #pragma unroll 8
    for (int d = 0; d < 64; ++d) {
      double vv = (double)xb[d * 2048 + c];
      s2 += vv * vv;
      dt += (double)xi[wv][d] * vv;
    }
    dkey[wv][lane] = s2 - 2.0 * dt;
  }
  __syncthreads();
  if (lane < 27) {
    double kl = dkey[wv][lane];
    int ci = cand[wv][lane];
    int rank = 0;
    for (int m = 0; m < 27; ++m) {
      double km = dkey[wv][m];
      int cm = cand[wv][m];
      if (km < kl || (km == kl && cm < ci)) ++rank;
    }
    if (rank < 20) idxout[(row0 + wv) * 20 + rank] = ci;
  }
}

// ---------------- conv1 (central-collapsed) -> h (bf16) ----------------
// h layout: [row=b*2048+n][c(256)][ko(10)] as bf16 pairs in uint
__global__ __launch_bounds__(256) void conv1_kernel(
    const float* __restrict__ x, const int* __restrict__ idxbuf,
    const float* __restrict__ w1nt, const float* __restrict__ U1t,
    uint* __restrict__ hu) {
  __shared__ float cen[4][64];
  __shared__ float nb[4][64][20];
  __shared__ int nidx[4][20];
  int tid = threadIdx.x;
  int p0 = blockIdx.x << 2;
  int b = p0 >> 11, n0 = p0 & 2047;
  if (tid < 80) { int p = tid / 20, j = tid - p * 20; nidx[p][j] = idxbuf[(p0 + p) * 20 + j]; }
  { int p = tid >> 6, d = tid & 63; cen[p][d] = x[b * 131072 + d * 2048 + n0 + p]; }
  __syncthreads();
  const float* xb = x + b * 131072;
  #pragma unroll
  for (int it = 0; it < 20; ++it) {
    int f = (it << 8) + tid;
    int p = f / 1280; int r = f - p * 1280; int d = r / 20; int j = r - d * 20;
    nb[p][d][j] = xb[d * 2048 + nidx[p][j]];
  }
  __syncthreads();
  int c = tid;
  float acc[4][10];
  #pragma unroll
  for (int p = 0; p < 4; ++p)
    #pragma unroll
    for (int ko = 0; ko < 10; ++ko) acc[p][ko] = 0.f;
  float ca[4] = {0.f, 0.f, 0.f, 0.f};
  for (int d = 0; d < 64; ++d) {
    float u = U1t[(d << 8) + c];
    float w[11];
    #pragma unroll
    for (int t = 0; t < 11; ++t) w[t] = w1nt[(d * 11 + t) * 256 + c];
    #pragma unroll
    for (int p = 0; p < 4; ++p) {
      ca[p] += cen[p][d] * u;
      float e[20];
      #pragma unroll
      for (int q = 0; q < 20; ++q) e[q] = nb[p][d][q];
      #pragma unroll
      for (int ko = 0; ko < 10; ++ko) {
        float s = acc[p][ko];
        #pragma unroll
        for (int t = 0; t < 11; ++t) s += w[t] * e[ko + t];
        acc[p][ko] = s;
      }
    }
  }
  #pragma unroll
  for (int p = 0; p < 4; ++p) {
    int base5 = ((p0 + p) * 256 + c) * 5;
    #pragma unroll
    for (int q = 0; q < 5; ++q) {
      float f0 = acc[p][2 * q] + ca[p];
      float f1 = acc[p][2 * q + 1] + ca[p];
      hu[base5 + q] = f2bf(f0) | (f2bf(f1) << 16);
    }
  }
}

// ---------------- BN stats ----------------
__global__ __launch_bounds__(256) void stats1_kernel(const uint* __restrict__ hu,
                                                     float* __restrict__ stats) {
  int c = threadIdx.x;
  float s = 0.f, ss = 0.f;
  for (int row = blockIdx.x; row < 16384; row += 128) {
    int base = (row * 256 + c) * 5;
    #pragma unroll
    for (int q = 0; q < 5; ++q) {
      uint v = hu[base + q];
      float f0 = bf2f(v & 0xffffu), f1 = bf2f(v >> 16);
      s += f0 + f1; ss += f0 * f0 + f1 * f1;
    }
  }
  atomicAdd(&stats[c], s);
  atomicAdd(&stats[256 + c], ss);
}

__global__ void finalize_kernel(const float* __restrict__ stats,
                                const float* __restrict__ gamma,
                                const float* __restrict__ beta,
                                float* __restrict__ coef, float inv_count) {
  int c = threadIdx.x;
  float m = stats[c] * inv_count;
  float var = stats[256 + c] * inv_count - m * m;
  float a = gamma[c] * rsqrtf(var + 1e-5f);
  coef[c] = a;
  coef[256 + c] = beta[c] - m * a;
}

// ---------------- conv2 as bf16 MFMA GEMM ----------------
// y[16384 x 256] = A[16384 x 3904] * W[3904 x 256]
// A row (point): [0,64)   central bf16(x)
//                [64,1344) neighbor gather bf16(x[d*2048+idx[p][j]]), q=d*20+j
//                [1344,3904) leaky(bn1(hu_flat[q'])), ch=q'/10
// Block: 32 points x 256 channels, 4 waves (wave w = 64-ch slice).
// A staged per-64-K chunk in LDS (double buffered, +8 pad); B-frags direct
// from global wpack (L2-resident, 2 MB).
__global__ __launch_bounds__(256) void conv2_mfma(
    const float* __restrict__ x, const int* __restrict__ idxbuf,
    const uint* __restrict__ hu, const float* __restrict__ coef1,
    const ushort* __restrict__ wpack, float* __restrict__ yraw) {
  __shared__ ushort As[2][32][72];   // +8 pad: 2-way (free) bank aliasing
  __shared__ int nidx[32][20];
  __shared__ float cf[512];
  int tid = threadIdx.x;
  int p0 = blockIdx.x << 5;          // 32 points per block
  int b = p0 >> 11, n0 = p0 & 2047;
  const float* xb = x + b * 131072;

  cf[tid] = coef1[tid];
  cf[256 + tid] = coef1[256 + tid];
  for (int v = tid; v < 640; v += 256) {
    int p = v / 20, j = v - p * 20;
    nidx[p][j] = idxbuf[(p0 + p) * 20 + j];
  }
  __syncthreads();

  auto build = [&](int kb, int buf) {
    if (kb == 0) {
      int p = tid >> 3;
      int d0 = (tid & 7) << 3;
      ushort o[8];
      #pragma unroll
      for (int i = 0; i < 8; ++i)
        o[i] = (ushort)f2bf(xb[(d0 + i) * 2048 + n0 + p]);
      *(short8*)&As[buf][p][d0] = *(short8*)o;
    } else if (kb < 21) {
      int v0 = tid << 3;
      int p = v0 >> 6, kk0 = v0 & 63;
      int qbase = (kb - 1) * 64 + kk0;
      ushort o[8];
      #pragma unroll
      for (int i = 0; i < 8; ++i) {
        int q = qbase + i;
        int d = q / 20, j = q - d * 20;
        o[i] = (ushort)f2bf(xb[d * 2048 + nidx[p][j]]);
      }
      *(short8*)&As[buf][p][kk0] = *(short8*)o;
    } else {
      int p = tid >> 3;
      int off = (tid & 7) << 3;
      int q0 = (kb - 21) * 64 + off;
      const uint* hp = hu + (size_t)(p0 + p) * 1280 + (q0 >> 1);
      uint4 hv = *(const uint4*)hp;
      float f[8];
      f[0] = bf2f(hv.x & 0xffffu); f[1] = bf2f(hv.x >> 16);
      f[2] = bf2f(hv.y & 0xffffu); f[3] = bf2f(hv.y >> 16);
      f[4] = bf2f(hv.z & 0xffffu); f[5] = bf2f(hv.z >> 16);
      f[6] = bf2f(hv.w & 0xffffu); f[7] = bf2f(hv.w >> 16);
      ushort o[8];
      #pragma unroll
      for (int i = 0; i < 8; ++i) {
        int ch = (q0 + i) / 10;
        float vv = f[i] * cf[ch] + cf[256 + ch];
        vv = vv > 0.f ? vv : 0.01f * vv;
        o[i] = (ushort)f2bf(vv);
      }
      *(short8*)&As[buf][p][off] = *(short8*)o;
    }
  };

  int lane = tid & 63, wave = tid >> 6;
  int m = lane & 15, quad = lane >> 4;
  int n0w = wave << 6;
  f32x4 acc[2][4] = {};

  build(0, 0);
  __syncthreads();
  for (int kb = 0; kb < 61; ++kb) {
    int buf = kb & 1;
    if (kb < 60) build(kb + 1, buf ^ 1);
    #pragma unroll
    for (int ks = 0; ks < 2; ++ks) {
      short8 afr0 = *(const short8*)&As[buf][m][ks * 32 + quad * 8];
      short8 afr1 = *(const short8*)&As[buf][16 + m][ks * 32 + quad * 8];
      #pragma unroll
      for (int nt = 0; nt < 4; ++nt) {
        const ushort* bp = wpack + (((size_t)kb << 14) |
                                    (uint)((n0w + nt * 16 + m) << 6) |
                                    (uint)(ks * 32 + quad * 8));
        short8 bfr = *(const short8*)bp;
        acc[0][nt] = __builtin_amdgcn_mfma_f32_16x16x32_bf16(afr0, bfr, acc[0][nt], 0, 0, 0);
        acc[1][nt] = __builtin_amdgcn_mfma_f32_16x16x32_bf16(afr1, bfr, acc[1][nt], 0, 0, 0);
      }
    }
    __syncthreads();
  }
  // epilogue: D layout col=lane&15, row=quad*4+r
  #pragma unroll
  for (int mt = 0; mt < 2; ++mt) {
    #pragma unroll
    for (int nt = 0; nt < 4; ++nt) {
      int col = n0w + nt * 16 + m;
      #pragma unroll
      for (int r = 0; r < 4; ++r) {
        int prow = mt * 16 + quad * 4 + r;
        yraw[(size_t)(p0 + prow) * 256 + col] = acc[mt][nt][r];
      }
    }
  }
}

__global__ __launch_bounds__(256) void stats2_kernel(const float* __restrict__ yraw,
                                                     float* __restrict__ stats) {
  int c = threadIdx.x;
  float s = 0.f, ss = 0.f;
  for (int row = blockIdx.x; row < 16384; row += 128) {
    float v = yraw[row * 256 + c];
    s += v; ss += v * v;
  }
  atomicAdd(&stats[c], s);
  atomicAdd(&stats[256 + c], ss);
}

// ---------------- BN2 + relu + transpose to (b, c, n) ----------------
__global__ __launch_bounds__(256) void out_kernel(const float* __restrict__ yraw,
                                                  const float* __restrict__ coef2,
                                                  float* __restrict__ out) {
  __shared__ float t[64][257];
  int tid = threadIdx.x;
  int blk = blockIdx.x;            // 256 = 8 b x 32 n-tiles
  int b = blk >> 5, n0 = (blk & 31) << 6;
  for (int it = 0; it < 64; ++it)
    t[it][tid] = yraw[(b * 2048 + n0 + it) * 256 + tid];
  __syncthreads();
  int nsub = tid & 63, cq = tid >> 6;
  for (int it = 0; it < 64; ++it) {
    int c = (it << 2) + cq;
    float v = coef2[c] * t[nsub][c] + coef2[256 + c];
    out[(b * 256 + c) * 2048 + n0 + nsub] = v > 0.f ? v : 0.f;
  }
}

extern "C" void kernel_launch(void* const* d_in, const int* in_sizes, int n_in,
                              void* d_out, int out_size, void* d_ws, size_t ws_size,
                              hipStream_t stream) {
  const float* x   = (const float*)d_in[0];
  const float* w1  = (const float*)d_in[1];
  const float* g1  = (const float*)d_in[3];
  const float* be1 = (const float*)d_in[4];
  const float* w2  = (const float*)d_in[5];
  const float* g2  = (const float*)d_in[7];
  const float* be2 = (const float*)d_in[8];
  float* out = (float*)d_out;
  char* w = (char*)d_ws;
  // workspace layout (~105 MB total)
  float* sqf   = (float*)(w);                  // 16384 * 4 (slot 131072 B)
  int*  idxbuf = (int*)(w + 131072);           // 327680 * 4     = 1310720
  uint* hu     = (uint*)(w + 1441792);         // h bf16: 83886080 B
  float* yraw  = (float*)(w + 85327872);       // 4194304 * 4    = 16777216
  float* stats = (float*)(w + 102105088);      // 4 * 256 floats
  float* coef  = (float*)(w + 102109184);      // 4 * 256 floats
  float* w1nt  = (float*)(w + 102113280);      // 180224 * 4
  float* U1t   = (float*)(w + 102834176);      // 16384 * 4
  ushort* wpack = (ushort*)(w + 102899712);    // 999424 * 2 -> end 104898560

  hipMemsetAsync(stats, 0, 4096, stream);
  prep_weights<<<4672, 256, 0, stream>>>(w1, w2, w1nt, U1t, wpack);
  sqnorm_kernel<<<64, 256, 0, stream>>>(x, sqf);
  knn_kernel<<<4096, 256, 0, stream>>>(x, sqf, idxbuf);
  conv1_kernel<<<4096, 256, 0, stream>>>(x, idxbuf, w1nt, U1t, hu);
  stats1_kernel<<<128, 256, 0, stream>>>(hu, stats);
  finalize_kernel<<<1, 256, 0, stream>>>(stats, g1, be1, coef, 1.f / 163840.f);
  conv2_mfma<<<512, 256, 0, stream>>>(x, idxbuf, hu, coef, wpack, yraw);
  stats2_kernel<<<128, 256, 0, stream>>>(yraw, stats + 512);
  finalize_kernel<<<1, 256, 0, stream>>>(stats + 512, g2, be2, coef + 512, 1.f / 16384.f);
  out_kernel<<<256, 256, 0, stream>>>(yraw, coef + 512, out);
}

// Round 5
// 1532.216 us; speedup vs baseline: 2.6105x; 1.6026x over previous
//
#include <hip/hip_runtime.h>
#include <stdint.h>

typedef unsigned int uint;
typedef unsigned short ushort;
typedef __attribute__((ext_vector_type(8))) short short8;
typedef __attribute__((ext_vector_type(4))) float f32x4;

__device__ __forceinline__ uint f2bf(float f) {
  uint u = __float_as_uint(f);
  return (u + 0x7fffu + ((u >> 16) & 1u)) >> 16;
}
__device__ __forceinline__ float bf2f(uint us) {
  return __uint_as_float(us << 16);
}

// ---------------- weight preprocessing ----------------
// w1: (256, 128, 1, 11)  w2: (256, 128, 1, 40)
// w1nt[d][t][c] = w1[c][64+d][t]           (64*11*256)
// U1t[d][c]     = sum_t (w1[c][d][t] - w1[c][64+d][t])
// wpack: conv2 GEMM B, bf16, layout [kb(61)][c(256)][kk(64)]; K order:
//   k<64: U2[d=k][c];  64<=k<1344: w2[c][64+d][j] (q=k-64=d*20+j);
//   1344<=k<3904: w2[c][ci][20+jj] (q=k-1344=ci*20+jj)
__global__ __launch_bounds__(256) void prep_weights(
    const float* __restrict__ w1, const float* __restrict__ w2,
    float* __restrict__ w1nt, float* __restrict__ U1t,
    ushort* __restrict__ wpack) {
  int g = blockIdx.x * 256 + threadIdx.x;
  if (g < 180224) {
    int d = g / 2816;
    int r = g - d * 2816;
    int t = r >> 8, c = r & 255;
    w1nt[g] = w1[c * 1408 + (64 + d) * 11 + t];
  } else if (g < 196608) {
    int q = g - 180224; int d = q >> 8, c = q & 255;
    float s = 0.f;
    for (int t = 0; t < 11; ++t)
      s += w1[c * 1408 + d * 11 + t] - w1[c * 1408 + (64 + d) * 11 + t];
    U1t[q] = s;
  } else {
    int gp = g - 196608;            // < 999424 = 61*16384
    int kb = gp >> 14;
    int r = gp & 16383;
    int c = r >> 6, kk = r & 63;
    int k = kb * 64 + kk;
    float val;
    if (k < 64) {
      int d = k;
      float s = 0.f;
      for (int j = 0; j < 20; ++j)
        s += w2[c * 5120 + d * 40 + j] - w2[c * 5120 + (64 + d) * 40 + j];
      val = s;
    } else if (k < 1344) {
      int q = k - 64; int d = q / 20, j = q - d * 20;
      val = w2[c * 5120 + (64 + d) * 40 + j];
    } else {
      int q = k - 1344; int ci = q / 20, jj = q - ci * 20;
      val = w2[c * 5120 + ci * 40 + 20 + jj];
    }
    wpack[gp] = (ushort)f2bf(val);
  }
}

// ---------------- squared norms (fp32, for the fp32 pre-selection only) ----------------
__global__ __launch_bounds__(256) void sqnorm_kernel(const float* __restrict__ x,
                                                     float* __restrict__ sqf) {
  int g = blockIdx.x * 256 + threadIdx.x;  // 16384
  int b = g >> 11, n = g & 2047;
  const float* xp = x + b * 131072 + n;
  float s = 0.f;
  #pragma unroll
  for (int d = 0; d < 64; ++d) { float v = xp[d * 2048]; s += v * v; }
  sqf[g] = s;
}

// ---------------- kNN v4: fp32 LDS dists + 2-reg local-min selection,
// ---------------- fp64 exact re-rank of the top-28 superset ----------------
__global__ __launch_bounds__(256) void knn_kernel(const float* __restrict__ x,
                                                  const float* __restrict__ sqf,
                                                  int* __restrict__ idxout) {
  __shared__ float xi[4][64];
  __shared__ float dist[4][2048];   // 32 KB
  __shared__ int cand[4][27];
  __shared__ double dkey[4][27];
  int tid = threadIdx.x;
  int row0 = blockIdx.x << 2;
  int b = row0 >> 11, n0 = row0 & 2047;
  { int r = tid >> 6, d = tid & 63; xi[r][d] = x[b * 131072 + d * 2048 + n0 + r]; }
  __syncthreads();
  const float* xb = x + b * 131072;
  const float* sqb = sqf + b * 2048;
  for (int jj = 0; jj < 8; ++jj) {
    int j = (jj << 8) + tid;
    float a0 = 0.f, a1 = 0.f, a2 = 0.f, a3 = 0.f;
    #pragma unroll 16
    for (int d = 0; d < 64; ++d) {
      float v = xb[d * 2048 + j];
      a0 += xi[0][d] * v; a1 += xi[1][d] * v; a2 += xi[2][d] * v; a3 += xi[3][d] * v;
    }
    float sqj = sqb[j];
    dist[0][j] = sqj - 2.f * a0;
    dist[1][j] = sqj - 2.f * a1;
    dist[2][j] = sqj - 2.f * a2;
    dist[3][j] = sqj - 2.f * a3;
  }
  __syncthreads();
  // ---- phase 2: wave per row; per-lane (lv,li) local min over its 32-col
  // strip (col = (l<<6)+lane); winner lane rescans from LDS after each pick.
  int wv = tid >> 6, lane = tid & 63;
  float* dr = dist[wv];
  float lv = 3e38f; int li = 0x7fffffff;
  #pragma unroll
  for (int l = 0; l < 32; ++l) {
    int jdx = (l << 6) + lane;
    float v = dr[jdx];
    if (v < lv) { lv = v; li = jdx; }
  }
  for (int pick = 0; pick < 28; ++pick) {
    float bv = lv; int bj = li;
    #pragma unroll
    for (int off = 32; off > 0; off >>= 1) {
      float ov = __shfl_xor(bv, off);
      int oj = __shfl_xor(bj, off);
      if (ov < bv || (ov == bv && oj < bj)) { bv = ov; bj = oj; }
    }
    if (pick > 0 && lane == 0) cand[wv][pick - 1] = bj;  // pick 0 == self
    if ((bj & 63) == lane) {
      dr[bj] = 3e38f;
      lv = 3e38f; li = 0x7fffffff;
      #pragma unroll
      for (int l = 0; l < 32; ++l) {
        int jdx = (l << 6) + lane;
        float v = dr[jdx];
        if (v < lv) { lv = v; li = jdx; }
      }
    }
  }
  __syncthreads();
  // ---- phase 3: fp64 exact keys for 27 candidates, rank, emit top-20
  if (lane < 27) {
    int c = cand[wv][lane];
    double dt = 0.0, s2 = 0.0;
    #pragma unroll 8
    for (int d = 0; d < 64; ++d) {
      double vv = (double)xb[d * 2048 + c];
      s2 += vv * vv;
      dt += (double)xi[wv][d] * vv;
    }
    dkey[wv][lane] = s2 - 2.0 * dt;
  }
  __syncthreads();
  if (lane < 27) {
    double kl = dkey[wv][lane];
    int ci = cand[wv][lane];
    int rank = 0;
    for (int m = 0; m < 27; ++m) {
      double km = dkey[wv][m];
      int cm = cand[wv][m];
      if (km < kl || (km == kl && cm < ci)) ++rank;
    }
    if (rank < 20) idxout[(row0 + wv) * 20 + rank] = ci;
  }
}

// ---------------- conv1 (central-collapsed) -> h (bf16) ----------------
// h layout: [row=b*2048+n][c(256)][ko(10)] as bf16 pairs in uint
__global__ __launch_bounds__(256) void conv1_kernel(
    const float* __restrict__ x, const int* __restrict__ idxbuf,
    const float* __restrict__ w1nt, const float* __restrict__ U1t,
    uint* __restrict__ hu) {
  __shared__ float cen[4][64];
  __shared__ float nb[4][64][20];
  __shared__ int nidx[4][20];
  int tid = threadIdx.x;
  int p0 = blockIdx.x << 2;
  int b = p0 >> 11, n0 = p0 & 2047;
  if (tid < 80) { int p = tid / 20, j = tid - p * 20; nidx[p][j] = idxbuf[(p0 + p) * 20 + j]; }
  { int p = tid >> 6, d = tid & 63; cen[p][d] = x[b * 131072 + d * 2048 + n0 + p]; }
  __syncthreads();
  const float* xb = x + b * 131072;
  #pragma unroll
  for (int it = 0; it < 20; ++it) {
    int f = (it << 8) + tid;
    int p = f / 1280; int r = f - p * 1280; int d = r / 20; int j = r - d * 20;
    nb[p][d][j] = xb[d * 2048 + nidx[p][j]];
  }
  __syncthreads();
  int c = tid;
  float acc[4][10];
  #pragma unroll
  for (int p = 0; p < 4; ++p)
    #pragma unroll
    for (int ko = 0; ko < 10; ++ko) acc[p][ko] = 0.f;
  float ca[4] = {0.f, 0.f, 0.f, 0.f};
  for (int d = 0; d < 64; ++d) {
    float u = U1t[(d << 8) + c];
    float w[11];
    #pragma unroll
    for (int t = 0; t < 11; ++t) w[t] = w1nt[(d * 11 + t) * 256 + c];
    #pragma unroll
    for (int p = 0; p < 4; ++p) {
      ca[p] += cen[p][d] * u;
      float e[20];
      #pragma unroll
      for (int q = 0; q < 20; ++q) e[q] = nb[p][d][q];
      #pragma unroll
      for (int ko = 0; ko < 10; ++ko) {
        float s = acc[p][ko];
        #pragma unroll
        for (int t = 0; t < 11; ++t) s += w[t] * e[ko + t];
        acc[p][ko] = s;
      }
    }
  }
  #pragma unroll
  for (int p = 0; p < 4; ++p) {
    int base5 = ((p0 + p) * 256 + c) * 5;
    #pragma unroll
    for (int q = 0; q < 5; ++q) {
      float f0 = acc[p][2 * q] + ca[p];
      float f1 = acc[p][2 * q + 1] + ca[p];
      hu[base5 + q] = f2bf(f0) | (f2bf(f1) << 16);
    }
  }
}

// ---------------- BN stats ----------------
__global__ __launch_bounds__(256) void stats1_kernel(const uint* __restrict__ hu,
                                                     float* __restrict__ stats) {
  int c = threadIdx.x;
  float s = 0.f, ss = 0.f;
  for (int row = blockIdx.x; row < 16384; row += 1024) {
    int base = (row * 256 + c) * 5;
    #pragma unroll
    for (int q = 0; q < 5; ++q) {
      uint v = hu[base + q];
      float f0 = bf2f(v & 0xffffu), f1 = bf2f(v >> 16);
      s += f0 + f1; ss += f0 * f0 + f1 * f1;
    }
  }
  atomicAdd(&stats[c], s);
  atomicAdd(&stats[256 + c], ss);
}

__global__ void finalize_kernel(const float* __restrict__ stats,
                                const float* __restrict__ gamma,
                                const float* __restrict__ beta,
                                float* __restrict__ coef, float inv_count) {
  int c = threadIdx.x;
  float m = stats[c] * inv_count;
  float var = stats[256 + c] * inv_count - m * m;
  float a = gamma[c] * rsqrtf(var + 1e-5f);
  coef[c] = a;
  coef[256 + c] = beta[c] - m * a;
}

// ---------------- conv2 as bf16 MFMA GEMM ----------------
__global__ __launch_bounds__(256) void conv2_mfma(
    const float* __restrict__ x, const int* __restrict__ idxbuf,
    const uint* __restrict__ hu, const float* __restrict__ coef1,
    const ushort* __restrict__ wpack, float* __restrict__ yraw) {
  __shared__ ushort As[2][32][72];   // +8 pad: 2-way (free) bank aliasing
  __shared__ int nidx[32][20];
  __shared__ float cf[512];
  int tid = threadIdx.x;
  int p0 = blockIdx.x << 5;          // 32 points per block
  int b = p0 >> 11, n0 = p0 & 2047;
  const float* xb = x + b * 131072;

  cf[tid] = coef1[tid];
  cf[256 + tid] = coef1[256 + tid];
  for (int v = tid; v < 640; v += 256) {
    int p = v / 20, j = v - p * 20;
    nidx[p][j] = idxbuf[(p0 + p) * 20 + j];
  }
  __syncthreads();

  auto build = [&](int kb, int buf) {
    if (kb == 0) {
      int p = tid >> 3;
      int d0 = (tid & 7) << 3;
      ushort o[8];
      #pragma unroll
      for (int i = 0; i < 8; ++i)
        o[i] = (ushort)f2bf(xb[(d0 + i) * 2048 + n0 + p]);
      *(short8*)&As[buf][p][d0] = *(short8*)o;
    } else if (kb < 21) {
      int v0 = tid << 3;
      int p = v0 >> 6, kk0 = v0 & 63;
      int qbase = (kb - 1) * 64 + kk0;
      ushort o[8];
      #pragma unroll
      for (int i = 0; i < 8; ++i) {
        int q = qbase + i;
        int d = q / 20, j = q - d * 20;
        o[i] = (ushort)f2bf(xb[d * 2048 + nidx[p][j]]);
      }
      *(short8*)&As[buf][p][kk0] = *(short8*)o;
    } else {
      int p = tid >> 3;
      int off = (tid & 7) << 3;
      int q0 = (kb - 21) * 64 + off;
      const uint* hp = hu + (size_t)(p0 + p) * 1280 + (q0 >> 1);
      uint4 hv = *(const uint4*)hp;
      float f[8];
      f[0] = bf2f(hv.x & 0xffffu); f[1] = bf2f(hv.x >> 16);
      f[2] = bf2f(hv.y & 0xffffu); f[3] = bf2f(hv.y >> 16);
      f[4] = bf2f(hv.z & 0xffffu); f[5] = bf2f(hv.z >> 16);
      f[6] = bf2f(hv.w & 0xffffu); f[7] = bf2f(hv.w >> 16);
      ushort o[8];
      #pragma unroll
      for (int i = 0; i < 8; ++i) {
        int ch = (q0 + i) / 10;
        float vv = f[i] * cf[ch] + cf[256 + ch];
        vv = vv > 0.f ? vv : 0.01f * vv;
        o[i] = (ushort)f2bf(vv);
      }
      *(short8*)&As[buf][p][off] = *(short8*)o;
    }
  };

  int lane = tid & 63, wave = tid >> 6;
  int m = lane & 15, quad = lane >> 4;
  int n0w = wave << 6;
  f32x4 acc[2][4] = {};

  build(0, 0);
  __syncthreads();
  for (int kb = 0; kb < 61; ++kb) {
    int buf = kb & 1;
    if (kb < 60) build(kb + 1, buf ^ 1);
    #pragma unroll
    for (int ks = 0; ks < 2; ++ks) {
      short8 afr0 = *(const short8*)&As[buf][m][ks * 32 + quad * 8];
      short8 afr1 = *(const short8*)&As[buf][16 + m][ks * 32 + quad * 8];
      #pragma unroll
      for (int nt = 0; nt < 4; ++nt) {
        const ushort* bp = wpack + (((size_t)kb << 14) |
                                    (uint)((n0w + nt * 16 + m) << 6) |
                                    (uint)(ks * 32 + quad * 8));
        short8 bfr = *(const short8*)bp;
        acc[0][nt] = __builtin_amdgcn_mfma_f32_16x16x32_bf16(afr0, bfr, acc[0][nt], 0, 0, 0);
        acc[1][nt] = __builtin_amdgcn_mfma_f32_16x16x32_bf16(afr1, bfr, acc[1][nt], 0, 0, 0);
      }
    }
    __syncthreads();
  }
  // epilogue: D layout col=lane&15, row=quad*4+r
  #pragma unroll
  for (int mt = 0; mt < 2; ++mt) {
    #pragma unroll
    for (int nt = 0; nt < 4; ++nt) {
      int col = n0w + nt * 16 + m;
      #pragma unroll
      for (int r = 0; r < 4; ++r) {
        int prow = mt * 16 + quad * 4 + r;
        yraw[(size_t)(p0 + prow) * 256 + col] = acc[mt][nt][r];
      }
    }
  }
}

__global__ __launch_bounds__(256) void stats2_kernel(const float* __restrict__ yraw,
                                                     float* __restrict__ stats) {
  int c = threadIdx.x;
  float s = 0.f, ss = 0.f;
  for (int row = blockIdx.x; row < 16384; row += 1024) {
    float v = yraw[row * 256 + c];
    s += v; ss += v * v;
  }
  atomicAdd(&stats[c], s);
  atomicAdd(&stats[256 + c], ss);
}

// ---------------- BN2 + relu + transpose to (b, c, n) ----------------
__global__ __launch_bounds__(256) void out_kernel(const float* __restrict__ yraw,
                                                  const float* __restrict__ coef2,
                                                  float* __restrict__ out) {
  __shared__ float t[64][257];
  int tid = threadIdx.x;
  int blk = blockIdx.x;            // 256 = 8 b x 32 n-tiles
  int b = blk >> 5, n0 = (blk & 31) << 6;
  for (int it = 0; it < 64; ++it)
    t[it][tid] = yraw[(b * 2048 + n0 + it) * 256 + tid];
  __syncthreads();
  int nsub = tid & 63, cq = tid >> 6;
  for (int it = 0; it < 64; ++it) {
    int c = (it << 2) + cq;
    float v = coef2[c] * t[nsub][c] + coef2[256 + c];
    out[(b * 256 + c) * 2048 + n0 + nsub] = v > 0.f ? v : 0.f;
  }
}

extern "C" void kernel_launch(void* const* d_in, const int* in_sizes, int n_in,
                              void* d_out, int out_size, void* d_ws, size_t ws_size,
                              hipStream_t stream) {
  const float* x   = (const float*)d_in[0];
  const float* w1  = (const float*)d_in[1];
  const float* g1  = (const float*)d_in[3];
  const float* be1 = (const float*)d_in[4];
  const float* w2  = (const float*)d_in[5];
  const float* g2  = (const float*)d_in[7];
  const float* be2 = (const float*)d_in[8];
  float* out = (float*)d_out;
  char* w = (char*)d_ws;
  // workspace layout (~105 MB total)
  float* sqf   = (float*)(w);                  // 16384 * 4 (slot 131072 B)
  int*  idxbuf = (int*)(w + 131072);           // 327680 * 4     = 1310720
  uint* hu     = (uint*)(w + 1441792);         // h bf16: 83886080 B
  float* yraw  = (float*)(w + 85327872);       // 4194304 * 4    = 16777216
  float* stats = (float*)(w + 102105088);      // 4 * 256 floats
  float* coef  = (float*)(w + 102109184);      // 4 * 256 floats
  float* w1nt  = (float*)(w + 102113280);      // 180224 * 4
  float* U1t   = (float*)(w + 102834176);      // 16384 * 4
  ushort* wpack = (ushort*)(w + 102899712);    // 999424 * 2 -> end 104898560

  hipMemsetAsync(stats, 0, 4096, stream);
  prep_weights<<<4672, 256, 0, stream>>>(w1, w2, w1nt, U1t, wpack);
  sqnorm_kernel<<<64, 256, 0, stream>>>(x, sqf);
  knn_kernel<<<4096, 256, 0, stream>>>(x, sqf, idxbuf);
  conv1_kernel<<<4096, 256, 0, stream>>>(x, idxbuf, w1nt, U1t, hu);
  stats1_kernel<<<1024, 256, 0, stream>>>(hu, stats);
  finalize_kernel<<<1, 256, 0, stream>>>(stats, g1, be1, coef, 1.f / 163840.f);
  conv2_mfma<<<512, 256, 0, stream>>>(x, idxbuf, hu, coef, wpack, yraw);
  stats2_kernel<<<1024, 256, 0, stream>>>(yraw, stats + 512);
  finalize_kernel<<<1, 256, 0, stream>>>(stats + 512, g2, be2, coef + 512, 1.f / 16384.f);
  out_kernel<<<256, 256, 0, stream>>>(yraw, coef + 512, out);
}

// Round 6
// 1024.814 us; speedup vs baseline: 3.9030x; 1.4951x over previous
//
#include <hip/hip_runtime.h>
#include <stdint.h>

typedef unsigned int uint;
typedef unsigned short ushort;
typedef __attribute__((ext_vector_type(8))) short short8;
typedef __attribute__((ext_vector_type(4))) float f32x4;

__device__ __forceinline__ uint f2bf(float f) {
  uint u = __float_as_uint(f);
  return (u + 0x7fffu + ((u >> 16) & 1u)) >> 16;
}
__device__ __forceinline__ float bf2f(uint us) {
  return __uint_as_float(us << 16);
}

// ---------------- weight preprocessing ----------------
// w1: (256, 128, 1, 11)  w2: (256, 128, 1, 40)
// wp1 (bf16): [t(11)][c(256)][d(64)] = w1[c][64+d][t]; then U block at
//   180224 + c*64 + d = sum_t (w1[c][d][t] - w1[c][64+d][t])
// wpack (bf16): conv2 GEMM B, layout [kb(61)][c(256)][kk(64)]; K order:
//   k<64: U2[d=k][c];  64<=k<1344: w2[c][64+d][j] (q=k-64=d*20+j);
//   1344<=k<3904: w2[c][ci][20+jj] (q=k-1344=ci*20+jj)
__global__ __launch_bounds__(256) void prep_weights(
    const float* __restrict__ w1, const float* __restrict__ w2,
    ushort* __restrict__ wp1, ushort* __restrict__ wpack) {
  int g = blockIdx.x * 256 + threadIdx.x;
  if (g < 180224) {
    int t = g >> 14;
    int r = g & 16383;
    int c = r >> 6, d = r & 63;
    wp1[g] = (ushort)f2bf(w1[c * 1408 + (64 + d) * 11 + t]);
  } else if (g < 196608) {
    int q = g - 180224;
    int c = q >> 6, d = q & 63;
    float s = 0.f;
    for (int t = 0; t < 11; ++t)
      s += w1[c * 1408 + d * 11 + t] - w1[c * 1408 + (64 + d) * 11 + t];
    wp1[g] = (ushort)f2bf(s);
  } else {
    int gp = g - 196608;            // < 999424 = 61*16384
    int kb = gp >> 14;
    int r = gp & 16383;
    int c = r >> 6, kk = r & 63;
    int k = kb * 64 + kk;
    float val;
    if (k < 64) {
      int d = k;
      float s = 0.f;
      for (int j = 0; j < 20; ++j)
        s += w2[c * 5120 + d * 40 + j] - w2[c * 5120 + (64 + d) * 40 + j];
      val = s;
    } else if (k < 1344) {
      int q = k - 64; int d = q / 20, j = q - d * 20;
      val = w2[c * 5120 + (64 + d) * 40 + j];
    } else {
      int q = k - 1344; int ci = q / 20, jj = q - ci * 20;
      val = w2[c * 5120 + ci * 40 + 20 + jj];
    }
    wpack[gp] = (ushort)f2bf(val);
  }
}

// ---------------- squared norms (fp32, for the fp32 pre-selection only) ----------------
__global__ __launch_bounds__(256) void sqnorm_kernel(const float* __restrict__ x,
                                                     float* __restrict__ sqf) {
  int g = blockIdx.x * 256 + threadIdx.x;  // 16384
  int b = g >> 11, n = g & 2047;
  const float* xp = x + b * 131072 + n;
  float s = 0.f;
  #pragma unroll
  for (int d = 0; d < 64; ++d) { float v = xp[d * 2048]; s += v * v; }
  sqf[g] = s;
}

// ---------------- kNN v4: fp32 LDS dists + 2-reg local-min selection,
// ---------------- fp64 exact re-rank of the top-28 superset ----------------
__global__ __launch_bounds__(256) void knn_kernel(const float* __restrict__ x,
                                                  const float* __restrict__ sqf,
                                                  int* __restrict__ idxout) {
  __shared__ float xi[4][64];
  __shared__ float dist[4][2048];   // 32 KB
  __shared__ int cand[4][27];
  __shared__ double dkey[4][27];
  int tid = threadIdx.x;
  int row0 = blockIdx.x << 2;
  int b = row0 >> 11, n0 = row0 & 2047;
  { int r = tid >> 6, d = tid & 63; xi[r][d] = x[b * 131072 + d * 2048 + n0 + r]; }
  __syncthreads();
  const float* xb = x + b * 131072;
  const float* sqb = sqf + b * 2048;
  for (int jj = 0; jj < 8; ++jj) {
    int j = (jj << 8) + tid;
    float a0 = 0.f, a1 = 0.f, a2 = 0.f, a3 = 0.f;
    #pragma unroll 16
    for (int d = 0; d < 64; ++d) {
      float v = xb[d * 2048 + j];
      a0 += xi[0][d] * v; a1 += xi[1][d] * v; a2 += xi[2][d] * v; a3 += xi[3][d] * v;
    }
    float sqj = sqb[j];
    dist[0][j] = sqj - 2.f * a0;
    dist[1][j] = sqj - 2.f * a1;
    dist[2][j] = sqj - 2.f * a2;
    dist[3][j] = sqj - 2.f * a3;
  }
  __syncthreads();
  int wv = tid >> 6, lane = tid & 63;
  float* dr = dist[wv];
  float lv = 3e38f; int li = 0x7fffffff;
  #pragma unroll
  for (int l = 0; l < 32; ++l) {
    int jdx = (l << 6) + lane;
    float v = dr[jdx];
    if (v < lv) { lv = v; li = jdx; }
  }
  for (int pick = 0; pick < 28; ++pick) {
    float bv = lv; int bj = li;
    #pragma unroll
    for (int off = 32; off > 0; off >>= 1) {
      float ov = __shfl_xor(bv, off);
      int oj = __shfl_xor(bj, off);
      if (ov < bv || (ov == bv && oj < bj)) { bv = ov; bj = oj; }
    }
    if (pick > 0 && lane == 0) cand[wv][pick - 1] = bj;  // pick 0 == self
    if ((bj & 63) == lane) {
      dr[bj] = 3e38f;
      lv = 3e38f; li = 0x7fffffff;
      #pragma unroll
      for (int l = 0; l < 32; ++l) {
        int jdx = (l << 6) + lane;
        float v = dr[jdx];
        if (v < lv) { lv = v; li = jdx; }
      }
    }
  }
  __syncthreads();
  if (lane < 27) {
    int c = cand[wv][lane];
    double dt = 0.0, s2 = 0.0;
    #pragma unroll 8
    for (int d = 0; d < 64; ++d) {
      double vv = (double)xb[d * 2048 + c];
      s2 += vv * vv;
      dt += (double)xi[wv][d] * vv;
    }
    dkey[wv][lane] = s2 - 2.0 * dt;
  }
  __syncthreads();
  if (lane < 27) {
    double kl = dkey[wv][lane];
    int ci = cand[wv][lane];
    int rank = 0;
    for (int m = 0; m < 27; ++m) {
      double km = dkey[wv][m];
      int cm = cand[wv][m];
      if (km < kl || (km == kl && cm < ci)) ++rank;
    }
    if (rank < 20) idxout[(row0 + wv) * 20 + rank] = ci;
  }
}

// ---------------- conv1 as bf16 MFMA (tap decomposition) ----------------
// h[p][c][ko] = sum_t slice_{ko+t}[p][:] . W_t[:][c]  +  central[p][:] . U1[:][c]
// Block: 16 points x 64 channels (4 waves x 16ch). 21 slices (central +
// 20 neighbors) staged once in LDS as bf16 [s][16][72]; main loop barrier-free.
__global__ __launch_bounds__(256) void conv1_mfma(
    const float* __restrict__ x, const int* __restrict__ idxbuf,
    const ushort* __restrict__ wp1, uint* __restrict__ hu) {
  __shared__ ushort sl[21][16][72];   // 48384 B; +8 pad -> free 2-way aliasing
  __shared__ int nidx[16][20];
  int tid = threadIdx.x;
  int pg = blockIdx.x >> 2;
  int cg = blockIdx.x & 3;
  int p0 = pg << 4;
  int b = p0 >> 11, n0 = p0 & 2047;
  const float* xb = x + b * 131072;
  for (int v = tid; v < 320; v += 256) {
    int p = v / 20, j = v - p * 20;
    nidx[p][j] = idxbuf[(p0 + p) * 20 + j];
  }
  __syncthreads();
  // stage 21*16*64 bf16 values as 10752 uint-pairs (42 per thread)
  for (int v = tid; v < 10752; v += 256) {
    int s = v >> 9;
    int r = v & 511;
    int p = r >> 5;
    int d0 = (r & 31) << 1;
    int col = (s == 0) ? (n0 + p) : nidx[p][s - 1];
    float f0 = xb[d0 * 2048 + col];
    float f1 = xb[(d0 + 1) * 2048 + col];
    *(uint*)&sl[s][p][d0] = f2bf(f0) | (f2bf(f1) << 16);
  }
  __syncthreads();
  int lane = tid & 63, wave = tid >> 6;
  int m = lane & 15, quad = lane >> 4;
  int cbase = (cg << 6) + (wave << 4);
  f32x4 acc[10] = {};
  f32x4 cacc = {};
  // central via U pack (block index 11 in wp1)
  {
    const ushort* urow = wp1 + 180224 + (cbase + m) * 64 + quad * 8;
    short8 a0 = *(const short8*)&sl[0][m][quad * 8];
    short8 a1 = *(const short8*)&sl[0][m][32 + quad * 8];
    short8 b0 = *(const short8*)(urow);
    short8 b1 = *(const short8*)(urow + 32);
    cacc = __builtin_amdgcn_mfma_f32_16x16x32_bf16(a0, b0, cacc, 0, 0, 0);
    cacc = __builtin_amdgcn_mfma_f32_16x16x32_bf16(a1, b1, cacc, 0, 0, 0);
  }
  #pragma unroll
  for (int t = 0; t < 11; ++t) {
    const ushort* brow = wp1 + t * 16384 + (cbase + m) * 64 + quad * 8;
    short8 b0 = *(const short8*)(brow);
    short8 b1 = *(const short8*)(brow + 32);
    #pragma unroll
    for (int ko = 0; ko < 10; ++ko) {
      int s = 1 + ko + t;
      short8 a0 = *(const short8*)&sl[s][m][quad * 8];
      short8 a1 = *(const short8*)&sl[s][m][32 + quad * 8];
      acc[ko] = __builtin_amdgcn_mfma_f32_16x16x32_bf16(a0, b0, acc[ko], 0, 0, 0);
      acc[ko] = __builtin_amdgcn_mfma_f32_16x16x32_bf16(a1, b1, acc[ko], 0, 0, 0);
    }
  }
  // epilogue: D layout col=lane&15 -> channel, row=quad*4+r -> point
  #pragma unroll
  for (int r = 0; r < 4; ++r) {
    int p = (quad << 2) + r;
    int c = cbase + m;
    int base5 = ((p0 + p) * 256 + c) * 5;
    float cc = cacc[r];
    #pragma unroll
    for (int q = 0; q < 5; ++q) {
      float f0 = acc[2 * q][r] + cc;
      float f1 = acc[2 * q + 1][r] + cc;
      hu[base5 + q] = f2bf(f0) | (f2bf(f1) << 16);
    }
  }
}

// ---------------- BN stats ----------------
__global__ __launch_bounds__(256) void stats1_kernel(const uint* __restrict__ hu,
                                                     float* __restrict__ stats) {
  int c = threadIdx.x;
  float s = 0.f, ss = 0.f;
  for (int row = blockIdx.x; row < 16384; row += 1024) {
    int base = (row * 256 + c) * 5;
    #pragma unroll
    for (int q = 0; q < 5; ++q) {
      uint v = hu[base + q];
      float f0 = bf2f(v & 0xffffu), f1 = bf2f(v >> 16);
      s += f0 + f1; ss += f0 * f0 + f1 * f1;
    }
  }
  atomicAdd(&stats[c], s);
  atomicAdd(&stats[256 + c], ss);
}

__global__ void finalize_kernel(const float* __restrict__ stats,
                                const float* __restrict__ gamma,
                                const float* __restrict__ beta,
                                float* __restrict__ coef, float inv_count) {
  int c = threadIdx.x;
  float m = stats[c] * inv_count;
  float var = stats[256 + c] * inv_count - m * m;
  float a = gamma[c] * rsqrtf(var + 1e-5f);
  coef[c] = a;
  coef[256 + c] = beta[c] - m * a;
}

// ---------------- conv2 as bf16 MFMA GEMM ----------------
__global__ __launch_bounds__(256) void conv2_mfma(
    const float* __restrict__ x, const int* __restrict__ idxbuf,
    const uint* __restrict__ hu, const float* __restrict__ coef1,
    const ushort* __restrict__ wpack, float* __restrict__ yraw) {
  __shared__ ushort As[2][32][72];   // +8 pad: 2-way (free) bank aliasing
  __shared__ int nidx[32][20];
  __shared__ float cf[512];
  int tid = threadIdx.x;
  int p0 = blockIdx.x << 5;          // 32 points per block
  int b = p0 >> 11, n0 = p0 & 2047;
  const float* xb = x + b * 131072;

  cf[tid] = coef1[tid];
  cf[256 + tid] = coef1[256 + tid];
  for (int v = tid; v < 640; v += 256) {
    int p = v / 20, j = v - p * 20;
    nidx[p][j] = idxbuf[(p0 + p) * 20 + j];
  }
  __syncthreads();

  auto build = [&](int kb, int buf) {
    if (kb == 0) {
      int p = tid >> 3;
      int d0 = (tid & 7) << 3;
      ushort o[8];
      #pragma unroll
      for (int i = 0; i < 8; ++i)
        o[i] = (ushort)f2bf(xb[(d0 + i) * 2048 + n0 + p]);
      *(short8*)&As[buf][p][d0] = *(short8*)o;
    } else if (kb < 21) {
      int v0 = tid << 3;
      int p = v0 >> 6, kk0 = v0 & 63;
      int qbase = (kb - 1) * 64 + kk0;
      ushort o[8];
      #pragma unroll
      for (int i = 0; i < 8; ++i) {
        int q = qbase + i;
        int d = q / 20, j = q - d * 20;
        o[i] = (ushort)f2bf(xb[d * 2048 + nidx[p][j]]);
      }
      *(short8*)&As[buf][p][kk0] = *(short8*)o;
    } else {
      int p = tid >> 3;
      int off = (tid & 7) << 3;
      int q0 = (kb - 21) * 64 + off;
      const uint* hp = hu + (size_t)(p0 + p) * 1280 + (q0 >> 1);
      uint4 hv = *(const uint4*)hp;
      float f[8];
      f[0] = bf2f(hv.x & 0xffffu); f[1] = bf2f(hv.x >> 16);
      f[2] = bf2f(hv.y & 0xffffu); f[3] = bf2f(hv.y >> 16);
      f[4] = bf2f(hv.z & 0xffffu); f[5] = bf2f(hv.z >> 16);
      f[6] = bf2f(hv.w & 0xffffu); f[7] = bf2f(hv.w >> 16);
      ushort o[8];
      #pragma unroll
      for (int i = 0; i < 8; ++i) {
        int ch = (q0 + i) / 10;
        float vv = f[i] * cf[ch] + cf[256 + ch];
        vv = vv > 0.f ? vv : 0.01f * vv;
        o[i] = (ushort)f2bf(vv);
      }
      *(short8*)&As[buf][p][off] = *(short8*)o;
    }
  };

  int lane = tid & 63, wave = tid >> 6;
  int m = lane & 15, quad = lane >> 4;
  int n0w = wave << 6;
  f32x4 acc[2][4] = {};

  build(0, 0);
  __syncthreads();
  for (int kb = 0; kb < 61; ++kb) {
    int buf = kb & 1;
    if (kb < 60) build(kb + 1, buf ^ 1);
    #pragma unroll
    for (int ks = 0; ks < 2; ++ks) {
      short8 afr0 = *(const short8*)&As[buf][m][ks * 32 + quad * 8];
      short8 afr1 = *(const short8*)&As[buf][16 + m][ks * 32 + quad * 8];
      #pragma unroll
      for (int nt = 0; nt < 4; ++nt) {
        const ushort* bp = wpack + (((size_t)kb << 14) |
                                    (uint)((n0w + nt * 16 + m) << 6) |
                                    (uint)(ks * 32 + quad * 8));
        short8 bfr = *(const short8*)bp;
        acc[0][nt] = __builtin_amdgcn_mfma_f32_16x16x32_bf16(afr0, bfr, acc[0][nt], 0, 0, 0);
        acc[1][nt] = __builtin_amdgcn_mfma_f32_16x16x32_bf16(afr1, bfr, acc[1][nt], 0, 0, 0);
      }
    }
    __syncthreads();
  }
  // epilogue: D layout col=lane&15, row=quad*4+r
  #pragma unroll
  for (int mt = 0; mt < 2; ++mt) {
    #pragma unroll
    for (int nt = 0; nt < 4; ++nt) {
      int col = n0w + nt * 16 + m;
      #pragma unroll
      for (int r = 0; r < 4; ++r) {
        int prow = mt * 16 + quad * 4 + r;
        yraw[(size_t)(p0 + prow) * 256 + col] = acc[mt][nt][r];
      }
    }
  }
}

__global__ __launch_bounds__(256) void stats2_kernel(const float* __restrict__ yraw,
                                                     float* __restrict__ stats) {
  int c = threadIdx.x;
  float s = 0.f, ss = 0.f;
  for (int row = blockIdx.x; row < 16384; row += 1024) {
    float v = yraw[row * 256 + c];
    s += v; ss += v * v;
  }
  atomicAdd(&stats[c], s);
  atomicAdd(&stats[256 + c], ss);
}

// ---------------- BN2 + relu + transpose to (b, c, n) ----------------
__global__ __launch_bounds__(256) void out_kernel(const float* __restrict__ yraw,
                                                  const float* __restrict__ coef2,
                                                  float* __restrict__ out) {
  __shared__ float t[64][257];
  int tid = threadIdx.x;
  int blk = blockIdx.x;            // 256 = 8 b x 32 n-tiles
  int b = blk >> 5, n0 = (blk & 31) << 6;
  for (int it = 0; it < 64; ++it)
    t[it][tid] = yraw[(b * 2048 + n0 + it) * 256 + tid];
  __syncthreads();
  int nsub = tid & 63, cq = tid >> 6;
  for (int it = 0; it < 64; ++it) {
    int c = (it << 2) + cq;
    float v = coef2[c] * t[nsub][c] + coef2[256 + c];
    out[(b * 256 + c) * 2048 + n0 + nsub] = v > 0.f ? v : 0.f;
  }
}

extern "C" void kernel_launch(void* const* d_in, const int* in_sizes, int n_in,
                              void* d_out, int out_size, void* d_ws, size_t ws_size,
                              hipStream_t stream) {
  const float* x   = (const float*)d_in[0];
  const float* w1  = (const float*)d_in[1];
  const float* g1  = (const float*)d_in[3];
  const float* be1 = (const float*)d_in[4];
  const float* w2  = (const float*)d_in[5];
  const float* g2  = (const float*)d_in[7];
  const float* be2 = (const float*)d_in[8];
  float* out = (float*)d_out;
  char* w = (char*)d_ws;
  // workspace layout (~105 MB total)
  float* sqf   = (float*)(w);                  // 16384 * 4 (slot 131072 B)
  int*  idxbuf = (int*)(w + 131072);           // 327680 * 4     = 1310720
  uint* hu     = (uint*)(w + 1441792);         // h bf16: 83886080 B
  float* yraw  = (float*)(w + 85327872);       // 4194304 * 4    = 16777216
  float* stats = (float*)(w + 102105088);      // 4 * 256 floats
  float* coef  = (float*)(w + 102109184);      // 4 * 256 floats
  ushort* wp1  = (ushort*)(w + 102113280);     // 196608 * 2 = 393216
  ushort* wpack = (ushort*)(w + 102506496);    // 999424 * 2 -> end 104505344

  hipMemsetAsync(stats, 0, 4096, stream);
  prep_weights<<<4672, 256, 0, stream>>>(w1, w2, wp1, wpack);
  sqnorm_kernel<<<64, 256, 0, stream>>>(x, sqf);
  knn_kernel<<<4096, 256, 0, stream>>>(x, sqf, idxbuf);
  conv1_mfma<<<4096, 256, 0, stream>>>(x, idxbuf, wp1, hu);
  stats1_kernel<<<1024, 256, 0, stream>>>(hu, stats);
  finalize_kernel<<<1, 256, 0, stream>>>(stats, g1, be1, coef, 1.f / 163840.f);
  conv2_mfma<<<512, 256, 0, stream>>>(x, idxbuf, hu, coef, wpack, yraw);
  stats2_kernel<<<1024, 256, 0, stream>>>(yraw, stats + 512);
  finalize_kernel<<<1, 256, 0, stream>>>(stats + 512, g2, be2, coef + 512, 1.f / 16384.f);
  out_kernel<<<256, 256, 0, stream>>>(yraw, coef + 512, out);
}

// Round 7
// 730.490 us; speedup vs baseline: 5.4756x; 1.4029x over previous
//
#include <hip/hip_runtime.h>
#include <stdint.h>

typedef unsigned int uint;
typedef unsigned short ushort;
typedef __attribute__((ext_vector_type(8))) short short8;
typedef __attribute__((ext_vector_type(4))) float f32x4;

__device__ __forceinline__ uint f2bf(float f) {
  uint u = __float_as_uint(f);
  return (u + 0x7fffu + ((u >> 16) & 1u)) >> 16;
}
__device__ __forceinline__ float bf2f(uint us) {
  return __uint_as_float(us << 16);
}

// ---------------- weight preprocessing ----------------
// w1: (256, 128, 1, 11)  w2: (256, 128, 1, 40)
// wp1 (bf16): [t(11)][c(256)][d(64)] = w1[c][64+d][t]; then U block at
//   180224 + c*64 + d = sum_t (w1[c][d][t] - w1[c][64+d][t])
// wpack (bf16): conv2 GEMM B, layout [kb(61)][c(256)][kk(64)]; K order:
//   k<64:        U2[d=k][c]
//   64<=k<1344:  j-major neighbor: j=(k-64)>>6, d=(k-64)&63 -> w2[c][64+d][j]
//   1344<=k<3904: interleave: q=k-1344=ci*20+jj -> w2[c][ci][20+jj]
__global__ __launch_bounds__(256) void prep_weights(
    const float* __restrict__ w1, const float* __restrict__ w2,
    ushort* __restrict__ wp1, ushort* __restrict__ wpack) {
  int g = blockIdx.x * 256 + threadIdx.x;
  if (g < 180224) {
    int t = g >> 14;
    int r = g & 16383;
    int c = r >> 6, d = r & 63;
    wp1[g] = (ushort)f2bf(w1[c * 1408 + (64 + d) * 11 + t]);
  } else if (g < 196608) {
    int q = g - 180224;
    int c = q >> 6, d = q & 63;
    float s = 0.f;
    for (int t = 0; t < 11; ++t)
      s += w1[c * 1408 + d * 11 + t] - w1[c * 1408 + (64 + d) * 11 + t];
    wp1[g] = (ushort)f2bf(s);
  } else {
    int gp = g - 196608;            // < 999424 = 61*16384
    int kb = gp >> 14;
    int r = gp & 16383;
    int c = r >> 6, kk = r & 63;
    int k = kb * 64 + kk;
    float val;
    if (k < 64) {
      int d = k;
      float s = 0.f;
      for (int j = 0; j < 20; ++j)
        s += w2[c * 5120 + d * 40 + j] - w2[c * 5120 + (64 + d) * 40 + j];
      val = s;
    } else if (k < 1344) {
      int q = k - 64; int j = q >> 6, d = q & 63;
      val = w2[c * 5120 + (64 + d) * 40 + j];
    } else {
      int q = k - 1344; int ci = q / 20, jj = q - ci * 20;
      val = w2[c * 5120 + ci * 40 + 20 + jj];
    }
    wpack[gp] = (ushort)f2bf(val);
  }
}

// ---------------- x transpose to bf16 [b][n][d] ----------------
__global__ __launch_bounds__(256) void transpose_x(const float* __restrict__ x,
                                                   uint* __restrict__ xtu) {
  __shared__ float t[64][65];
  int tid = threadIdx.x;
  int blk = blockIdx.x;            // 256 = 8 b x 32 n-tiles
  int b = blk >> 5, n0 = (blk & 31) << 6;
  const float* xb = x + b * 131072;
  #pragma unroll
  for (int it = 0; it < 16; ++it) {
    int d = (it << 2) + (tid >> 6);
    int n = tid & 63;
    t[d][n] = xb[d * 2048 + n0 + n];
  }
  __syncthreads();
  #pragma unroll
  for (int it = 0; it < 8; ++it) {
    int n = (it << 3) + (tid >> 5);
    int dp = tid & 31;
    uint v = f2bf(t[2 * dp][n]) | (f2bf(t[2 * dp + 1][n]) << 16);
    xtu[(size_t)(b * 2048 + n0 + n) * 32 + dp] = v;
  }
}

// ---------------- squared norms (fp32, for the fp32 pre-selection only) ----------------
__global__ __launch_bounds__(256) void sqnorm_kernel(const float* __restrict__ x,
                                                     float* __restrict__ sqf) {
  int g = blockIdx.x * 256 + threadIdx.x;  // 16384
  int b = g >> 11, n = g & 2047;
  const float* xp = x + b * 131072 + n;
  float s = 0.f;
  #pragma unroll
  for (int d = 0; d < 64; ++d) { float v = xp[d * 2048]; s += v * v; }
  sqf[g] = s;
}

// ---------------- kNN v4: fp32 LDS dists + 2-reg local-min selection,
// ---------------- fp64 exact re-rank of the top-28 superset ----------------
__global__ __launch_bounds__(256) void knn_kernel(const float* __restrict__ x,
                                                  const float* __restrict__ sqf,
                                                  int* __restrict__ idxout) {
  __shared__ float xi[4][64];
  __shared__ float dist[4][2048];   // 32 KB
  __shared__ int cand[4][27];
  __shared__ double dkey[4][27];
  int tid = threadIdx.x;
  int row0 = blockIdx.x << 2;
  int b = row0 >> 11, n0 = row0 & 2047;
  { int r = tid >> 6, d = tid & 63; xi[r][d] = x[b * 131072 + d * 2048 + n0 + r]; }
  __syncthreads();
  const float* xb = x + b * 131072;
  const float* sqb = sqf + b * 2048;
  for (int jj = 0; jj < 8; ++jj) {
    int j = (jj << 8) + tid;
    float a0 = 0.f, a1 = 0.f, a2 = 0.f, a3 = 0.f;
    #pragma unroll 16
    for (int d = 0; d < 64; ++d) {
      float v = xb[d * 2048 + j];
      a0 += xi[0][d] * v; a1 += xi[1][d] * v; a2 += xi[2][d] * v; a3 += xi[3][d] * v;
    }
    float sqj = sqb[j];
    dist[0][j] = sqj - 2.f * a0;
    dist[1][j] = sqj - 2.f * a1;
    dist[2][j] = sqj - 2.f * a2;
    dist[3][j] = sqj - 2.f * a3;
  }
  __syncthreads();
  int wv = tid >> 6, lane = tid & 63;
  float* dr = dist[wv];
  float lv = 3e38f; int li = 0x7fffffff;
  #pragma unroll
  for (int l = 0; l < 32; ++l) {
    int jdx = (l << 6) + lane;
    float v = dr[jdx];
    if (v < lv) { lv = v; li = jdx; }
  }
  for (int pick = 0; pick < 28; ++pick) {
    float bv = lv; int bj = li;
    #pragma unroll
    for (int off = 32; off > 0; off >>= 1) {
      float ov = __shfl_xor(bv, off);
      int oj = __shfl_xor(bj, off);
      if (ov < bv || (ov == bv && oj < bj)) { bv = ov; bj = oj; }
    }
    if (pick > 0 && lane == 0) cand[wv][pick - 1] = bj;  // pick 0 == self
    if ((bj & 63) == lane) {
      dr[bj] = 3e38f;
      lv = 3e38f; li = 0x7fffffff;
      #pragma unroll
      for (int l = 0; l < 32; ++l) {
        int jdx = (l << 6) + lane;
        float v = dr[jdx];
        if (v < lv) { lv = v; li = jdx; }
      }
    }
  }
  __syncthreads();
  if (lane < 27) {
    int c = cand[wv][lane];
    double dt = 0.0, s2 = 0.0;
    #pragma unroll 8
    for (int d = 0; d < 64; ++d) {
      double vv = (double)xb[d * 2048 + c];
      s2 += vv * vv;
      dt += (double)xi[wv][d] * vv;
    }
    dkey[wv][lane] = s2 - 2.0 * dt;
  }
  __syncthreads();
  if (lane < 27) {
    double kl = dkey[wv][lane];
    int ci = cand[wv][lane];
    int rank = 0;
    for (int m = 0; m < 27; ++m) {
      double km = dkey[wv][m];
      int cm = cand[wv][m];
      if (km < kl || (km == kl && cm < ci)) ++rank;
    }
    if (rank < 20) idxout[(row0 + wv) * 20 + rank] = ci;
  }
}

// ---------------- conv1 as bf16 MFMA (tap decomposition, xT staging) ----------------
// Block: 16 points x 128 channels (4 waves x 2 col-tiles of 16ch). 21 slices
// staged once from xbf_t as contiguous 128-B columns; main loop barrier-free.
__global__ __launch_bounds__(256) void conv1_mfma(
    const ushort* __restrict__ xbf_t, const int* __restrict__ idxbuf,
    const ushort* __restrict__ wp1, uint* __restrict__ hu) {
  __shared__ ushort sl[21][16][72];   // 48384 B; rows 144 B (16-B aligned)
  __shared__ int nidx[16][20];
  int tid = threadIdx.x;
  int pg = blockIdx.x >> 1;
  int cg = blockIdx.x & 1;
  int p0 = pg << 4;
  int b = p0 >> 11, n0 = p0 & 2047;
  const ushort* xt = xbf_t + ((size_t)b << 17);
  for (int v = tid; v < 320; v += 256) {
    int p = v / 20, j = v - p * 20;
    nidx[p][j] = idxbuf[(p0 + p) * 20 + j];
  }
  __syncthreads();
  // 21 slices x 16 points x 8 chunks of short8
  for (int v = tid; v < 2688; v += 256) {
    int s = v >> 7;
    int r = v & 127;
    int p = r >> 3, i = r & 7;
    int col = (s == 0) ? (n0 + p) : nidx[p][s - 1];
    *(short8*)&sl[s][p][i << 3] =
        *(const short8*)(xt + ((size_t)col << 6) + (i << 3));
  }
  __syncthreads();
  int lane = tid & 63, wave = tid >> 6;
  int m = lane & 15, quad = lane >> 4;
  int ch0 = (cg << 7) + (wave << 4) + m;    // + ct*64
  f32x4 acc[10][2] = {};
  f32x4 cacc[2] = {};
  {
    short8 a0 = *(const short8*)&sl[0][m][quad * 8];
    short8 a1 = *(const short8*)&sl[0][m][32 + quad * 8];
    #pragma unroll
    for (int ct = 0; ct < 2; ++ct) {
      const ushort* urow = wp1 + 180224 + (ch0 + ct * 64) * 64 + quad * 8;
      short8 b0 = *(const short8*)(urow);
      short8 b1 = *(const short8*)(urow + 32);
      cacc[ct] = __builtin_amdgcn_mfma_f32_16x16x32_bf16(a0, b0, cacc[ct], 0, 0, 0);
      cacc[ct] = __builtin_amdgcn_mfma_f32_16x16x32_bf16(a1, b1, cacc[ct], 0, 0, 0);
    }
  }
  #pragma unroll
  for (int t = 0; t < 11; ++t) {
    short8 b0[2], b1[2];
    #pragma unroll
    for (int ct = 0; ct < 2; ++ct) {
      const ushort* brow = wp1 + t * 16384 + (ch0 + ct * 64) * 64 + quad * 8;
      b0[ct] = *(const short8*)(brow);
      b1[ct] = *(const short8*)(brow + 32);
    }
    #pragma unroll
    for (int ko = 0; ko < 10; ++ko) {
      int s = 1 + ko + t;
      short8 a0 = *(const short8*)&sl[s][m][quad * 8];
      short8 a1 = *(const short8*)&sl[s][m][32 + quad * 8];
      #pragma unroll
      for (int ct = 0; ct < 2; ++ct) {
        acc[ko][ct] = __builtin_amdgcn_mfma_f32_16x16x32_bf16(a0, b0[ct], acc[ko][ct], 0, 0, 0);
        acc[ko][ct] = __builtin_amdgcn_mfma_f32_16x16x32_bf16(a1, b1[ct], acc[ko][ct], 0, 0, 0);
      }
    }
  }
  // epilogue: D layout col=lane&15 -> channel, row=quad*4+r -> point
  #pragma unroll
  for (int ct = 0; ct < 2; ++ct) {
    int c = ch0 + ct * 64;
    #pragma unroll
    for (int r = 0; r < 4; ++r) {
      int p = (quad << 2) + r;
      int base5 = ((p0 + p) * 256 + c) * 5;
      float cc = cacc[ct][r];
      #pragma unroll
      for (int q = 0; q < 5; ++q) {
        float f0 = acc[2 * q][ct][r] + cc;
        float f1 = acc[2 * q + 1][ct][r] + cc;
        hu[base5 + q] = f2bf(f0) | (f2bf(f1) << 16);
      }
    }
  }
}

// ---------------- BN stats ----------------
__global__ __launch_bounds__(256) void stats1_kernel(const uint* __restrict__ hu,
                                                     float* __restrict__ stats) {
  int c = threadIdx.x;
  float s = 0.f, ss = 0.f;
  for (int row = blockIdx.x; row < 16384; row += 1024) {
    int base = (row * 256 + c) * 5;
    #pragma unroll
    for (int q = 0; q < 5; ++q) {
      uint v = hu[base + q];
      float f0 = bf2f(v & 0xffffu), f1 = bf2f(v >> 16);
      s += f0 + f1; ss += f0 * f0 + f1 * f1;
    }
  }
  atomicAdd(&stats[c], s);
  atomicAdd(&stats[256 + c], ss);
}

__global__ void finalize_kernel(const float* __restrict__ stats,
                                const float* __restrict__ gamma,
                                const float* __restrict__ beta,
                                float* __restrict__ coef, float inv_count) {
  int c = threadIdx.x;
  float m = stats[c] * inv_count;
  float var = stats[256 + c] * inv_count - m * m;
  float a = gamma[c] * rsqrtf(var + 1e-5f);
  coef[c] = a;
  coef[256 + c] = beta[c] - m * a;
}

// ---------------- conv2 as bf16 MFMA GEMM (xT staging) ----------------
__global__ __launch_bounds__(256) void conv2_mfma(
    const ushort* __restrict__ xbf_t, const int* __restrict__ idxbuf,
    const uint* __restrict__ hu, const float* __restrict__ coef1,
    const ushort* __restrict__ wpack, float* __restrict__ yraw) {
  __shared__ ushort As[2][32][72];
  __shared__ int nidx[32][20];
  __shared__ float cf[512];
  int tid = threadIdx.x;
  int p0 = blockIdx.x << 5;          // 32 points per block
  int b = p0 >> 11, n0 = p0 & 2047;
  const ushort* xt = xbf_t + ((size_t)b << 17);

  cf[tid] = coef1[tid];
  cf[256 + tid] = coef1[256 + tid];
  for (int v = tid; v < 640; v += 256) {
    int p = v / 20, j = v - p * 20;
    nidx[p][j] = idxbuf[(p0 + p) * 20 + j];
  }
  __syncthreads();

  auto build = [&](int kb, int buf) {
    if (kb < 21) {
      // one column (central or neighbor kb-1) per point, contiguous in xT
      int p = tid >> 3, i = tid & 7;
      int col = (kb == 0) ? (n0 + p) : nidx[p][kb - 1];
      *(short8*)&As[buf][p][i << 3] =
          *(const short8*)(xt + ((size_t)col << 6) + (i << 3));
    } else {
      int p = tid >> 3;
      int off = (tid & 7) << 3;
      int q0 = (kb - 21) * 64 + off;
      const uint* hp = hu + (size_t)(p0 + p) * 1280 + (q0 >> 1);
      uint4 hv = *(const uint4*)hp;
      float f[8];
      f[0] = bf2f(hv.x & 0xffffu); f[1] = bf2f(hv.x >> 16);
      f[2] = bf2f(hv.y & 0xffffu); f[3] = bf2f(hv.y >> 16);
      f[4] = bf2f(hv.z & 0xffffu); f[5] = bf2f(hv.z >> 16);
      f[6] = bf2f(hv.w & 0xffffu); f[7] = bf2f(hv.w >> 16);
      ushort o[8];
      #pragma unroll
      for (int i = 0; i < 8; ++i) {
        int ch = (q0 + i) / 10;
        float vv = f[i] * cf[ch] + cf[256 + ch];
        vv = vv > 0.f ? vv : 0.01f * vv;
        o[i] = (ushort)f2bf(vv);
      }
      *(short8*)&As[buf][p][off] = *(short8*)o;
    }
  };

  int lane = tid & 63, wave = tid >> 6;
  int m = lane & 15, quad = lane >> 4;
  int n0w = wave << 6;
  f32x4 acc[2][4] = {};

  build(0, 0);
  __syncthreads();
  for (int kb = 0; kb < 61; ++kb) {
    int buf = kb & 1;
    if (kb < 60) build(kb + 1, buf ^ 1);
    #pragma unroll
    for (int ks = 0; ks < 2; ++ks) {
      short8 afr0 = *(const short8*)&As[buf][m][ks * 32 + quad * 8];
      short8 afr1 = *(const short8*)&As[buf][16 + m][ks * 32 + quad * 8];
      #pragma unroll
      for (int nt = 0; nt < 4; ++nt) {
        const ushort* bp = wpack + (((size_t)kb << 14) |
                                    (uint)((n0w + nt * 16 + m) << 6) |
                                    (uint)(ks * 32 + quad * 8));
        short8 bfr = *(const short8*)bp;
        acc[0][nt] = __builtin_amdgcn_mfma_f32_16x16x32_bf16(afr0, bfr, acc[0][nt], 0, 0, 0);
        acc[1][nt] = __builtin_amdgcn_mfma_f32_16x16x32_bf16(afr1, bfr, acc[1][nt], 0, 0, 0);
      }
    }
    __syncthreads();
  }
  #pragma unroll
  for (int mt = 0; mt < 2; ++mt) {
    #pragma unroll
    for (int nt = 0; nt < 4; ++nt) {
      int col = n0w + nt * 16 + m;
      #pragma unroll
      for (int r = 0; r < 4; ++r) {
        int prow = mt * 16 + quad * 4 + r;
        yraw[(size_t)(p0 + prow) * 256 + col] = acc[mt][nt][r];
      }
    }
  }
}

__global__ __launch_bounds__(256) void stats2_kernel(const float* __restrict__ yraw,
                                                     float* __restrict__ stats) {
  int c = threadIdx.x;
  float s = 0.f, ss = 0.f;
  for (int row = blockIdx.x; row < 16384; row += 1024) {
    float v = yraw[row * 256 + c];
    s += v; ss += v * v;
  }
  atomicAdd(&stats[c], s);
  atomicAdd(&stats[256 + c], ss);
}

// ---------------- BN2 + relu + transpose to (b, c, n) ----------------
__global__ __launch_bounds__(256) void out_kernel(const float* __restrict__ yraw,
                                                  const float* __restrict__ coef2,
                                                  float* __restrict__ out) {
  __shared__ float t[64][257];
  int tid = threadIdx.x;
  int blk = blockIdx.x;            // 256 = 8 b x 32 n-tiles
  int b = blk >> 5, n0 = (blk & 31) << 6;
  for (int it = 0; it < 64; ++it)
    t[it][tid] = yraw[(b * 2048 + n0 + it) * 256 + tid];
  __syncthreads();
  int nsub = tid & 63, cq = tid >> 6;
  for (int it = 0; it < 64; ++it) {
    int c = (it << 2) + cq;
    float v = coef2[c] * t[nsub][c] + coef2[256 + c];
    out[(b * 256 + c) * 2048 + n0 + nsub] = v > 0.f ? v : 0.f;
  }
}

extern "C" void kernel_launch(void* const* d_in, const int* in_sizes, int n_in,
                              void* d_out, int out_size, void* d_ws, size_t ws_size,
                              hipStream_t stream) {
  const float* x   = (const float*)d_in[0];
  const float* w1  = (const float*)d_in[1];
  const float* g1  = (const float*)d_in[3];
  const float* be1 = (const float*)d_in[4];
  const float* w2  = (const float*)d_in[5];
  const float* g2  = (const float*)d_in[7];
  const float* be2 = (const float*)d_in[8];
  float* out = (float*)d_out;
  char* w = (char*)d_ws;
  // workspace layout (~106.6 MB total)
  float* sqf    = (float*)(w);                 // 16384 * 4 (slot 131072 B)
  int*  idxbuf  = (int*)(w + 131072);          // 327680 * 4     = 1310720
  uint* hu      = (uint*)(w + 1441792);        // h bf16: 83886080 B
  float* yraw   = (float*)(w + 85327872);      // 4194304 * 4    = 16777216
  float* stats  = (float*)(w + 102105088);     // 4 * 256 floats
  float* coef   = (float*)(w + 102109184);     // 4 * 256 floats
  ushort* wp1   = (ushort*)(w + 102113280);    // 196608 * 2 = 393216
  ushort* wpack = (ushort*)(w + 102506496);    // 999424 * 2 = 1998848
  ushort* xbf_t = (ushort*)(w + 104505344);    // 1048576 * 2 -> end 106602496

  hipMemsetAsync(stats, 0, 4096, stream);
  prep_weights<<<4672, 256, 0, stream>>>(w1, w2, wp1, wpack);
  transpose_x<<<256, 256, 0, stream>>>(x, (uint*)xbf_t);
  sqnorm_kernel<<<64, 256, 0, stream>>>(x, sqf);
  knn_kernel<<<4096, 256, 0, stream>>>(x, sqf, idxbuf);
  conv1_mfma<<<2048, 256, 0, stream>>>(xbf_t, idxbuf, wp1, hu);
  stats1_kernel<<<1024, 256, 0, stream>>>(hu, stats);
  finalize_kernel<<<1, 256, 0, stream>>>(stats, g1, be1, coef, 1.f / 163840.f);
  conv2_mfma<<<512, 256, 0, stream>>>(xbf_t, idxbuf, hu, coef, wpack, yraw);
  stats2_kernel<<<1024, 256, 0, stream>>>(yraw, stats + 512);
  finalize_kernel<<<1, 256, 0, stream>>>(stats + 512, g2, be2, coef + 512, 1.f / 16384.f);
  out_kernel<<<256, 256, 0, stream>>>(yraw, coef + 512, out);
}

// Round 8
// 691.213 us; speedup vs baseline: 5.7868x; 1.0568x over previous
//
#include <hip/hip_runtime.h>
#include <stdint.h>

typedef unsigned int uint;
typedef unsigned short ushort;
typedef __attribute__((ext_vector_type(8))) short short8;
typedef __attribute__((ext_vector_type(4))) float f32x4;

__device__ __forceinline__ uint f2bf(float f) {
  uint u = __float_as_uint(f);
  return (u + 0x7fffu + ((u >> 16) & 1u)) >> 16;
}
__device__ __forceinline__ float bf2f(uint us) {
  return __uint_as_float(us << 16);
}

// ---------------- weight preprocessing ----------------
// w1: (256, 128, 1, 11)  w2: (256, 128, 1, 40)
// wp1 (bf16): [t(11)][c(256)][d(64)] = w1[c][64+d][t]; then U block at
//   180224 + c*64 + d = sum_t (w1[c][d][t] - w1[c][64+d][t])
// wpack (bf16): conv2 GEMM B, layout [kb(61)][c(256)][kk(64)]; K order:
//   k<64:        U2[d=k][c]
//   64<=k<1344:  j-major neighbor: j=(k-64)>>6, d=(k-64)&63 -> w2[c][64+d][j]
//   1344<=k<3904: interleave: q=k-1344=ci*20+jj -> w2[c][ci][20+jj]
__global__ __launch_bounds__(256) void prep_weights(
    const float* __restrict__ w1, const float* __restrict__ w2,
    ushort* __restrict__ wp1, ushort* __restrict__ wpack) {
  int g = blockIdx.x * 256 + threadIdx.x;
  if (g < 180224) {
    int t = g >> 14;
    int r = g & 16383;
    int c = r >> 6, d = r & 63;
    wp1[g] = (ushort)f2bf(w1[c * 1408 + (64 + d) * 11 + t]);
  } else if (g < 196608) {
    int q = g - 180224;
    int c = q >> 6, d = q & 63;
    float s = 0.f;
    for (int t = 0; t < 11; ++t)
      s += w1[c * 1408 + d * 11 + t] - w1[c * 1408 + (64 + d) * 11 + t];
    wp1[g] = (ushort)f2bf(s);
  } else {
    int gp = g - 196608;            // < 999424 = 61*16384
    int kb = gp >> 14;
    int r = gp & 16383;
    int c = r >> 6, kk = r & 63;
    int k = kb * 64 + kk;
    float val;
    if (k < 64) {
      int d = k;
      float s = 0.f;
      for (int j = 0; j < 20; ++j)
        s += w2[c * 5120 + d * 40 + j] - w2[c * 5120 + (64 + d) * 40 + j];
      val = s;
    } else if (k < 1344) {
      int q = k - 64; int j = q >> 6, d = q & 63;
      val = w2[c * 5120 + (64 + d) * 40 + j];
    } else {
      int q = k - 1344; int ci = q / 20, jj = q - ci * 20;
      val = w2[c * 5120 + ci * 40 + 20 + jj];
    }
    wpack[gp] = (ushort)f2bf(val);
  }
}

// ---------------- x transpose to bf16 [b][n][d] ----------------
__global__ __launch_bounds__(256) void transpose_x(const float* __restrict__ x,
                                                   uint* __restrict__ xtu) {
  __shared__ float t[64][65];
  int tid = threadIdx.x;
  int blk = blockIdx.x;            // 256 = 8 b x 32 n-tiles
  int b = blk >> 5, n0 = (blk & 31) << 6;
  const float* xb = x + b * 131072;
  #pragma unroll
  for (int it = 0; it < 16; ++it) {
    int d = (it << 2) + (tid >> 6);
    int n = tid & 63;
    t[d][n] = xb[d * 2048 + n0 + n];
  }
  __syncthreads();
  #pragma unroll
  for (int it = 0; it < 8; ++it) {
    int n = (it << 3) + (tid >> 5);
    int dp = tid & 31;
    uint v = f2bf(t[2 * dp][n]) | (f2bf(t[2 * dp + 1][n]) << 16);
    xtu[(size_t)(b * 2048 + n0 + n) * 32 + dp] = v;
  }
}

// ---------------- squared norms (fp32, for the fp32 pre-selection only) ----------------
__global__ __launch_bounds__(256) void sqnorm_kernel(const float* __restrict__ x,
                                                     float* __restrict__ sqf) {
  int g = blockIdx.x * 256 + threadIdx.x;  // 16384
  int b = g >> 11, n = g & 2047;
  const float* xp = x + b * 131072 + n;
  float s = 0.f;
  #pragma unroll
  for (int d = 0; d < 64; ++d) { float v = xp[d * 2048]; s += v * v; }
  sqf[g] = s;
}

// ---------------- kNN v5: MFMA distance tiles + 2-candidate selection,
// ---------------- fp64 exact re-rank of a top-32 superset ----------------
// Block: 16 rows x 2048 cols, 1024 threads (16 waves). Phase 1: G = X^T X via
// bf16 MFMA (A and B frags are contiguous 128-B columns of xbf_t); dist =
// sqf[j] - 2G into LDS (fp32). Phase 2: wave wv selects 32 smallest of row wv
// (lane keeps 2 smallest of its 32-col strip; win promotes spare; rescan only
// on a lane's 2nd win). Phase 3: fp64 exact keys for the 31 non-self
// candidates; ranks 0..19 are the output (reproduces fp64-reference order).
__global__ __launch_bounds__(1024) void knn_kernel(
    const float* __restrict__ x, const ushort* __restrict__ xbf_t,
    const float* __restrict__ sqf, int* __restrict__ idxout) {
  __shared__ float dist[16][2048];   // 128 KB
  __shared__ int cand[16][31];
  __shared__ double dkey[16][31];
  int tid = threadIdx.x;
  int wv = tid >> 6, lane = tid & 63;
  int row0 = blockIdx.x << 4;
  int b = row0 >> 11, n0 = row0 & 2047;
  const ushort* xt = xbf_t + ((size_t)b << 17);
  const float* sqb = sqf + (b << 11);
  int m = lane & 15, quad = lane >> 4;
  // A-frags: 16 block rows
  short8 afr0 = *(const short8*)(xt + ((size_t)(n0 + m) << 6) + quad * 8);
  short8 afr1 = *(const short8*)(xt + ((size_t)(n0 + m) << 6) + 32 + quad * 8);
  // phase 1: wave wv computes col-tiles [wv*8, wv*8+8)
  for (int t = 0; t < 8; ++t) {
    int col = (((wv << 3) + t) << 4) + m;
    short8 bfr0 = *(const short8*)(xt + ((size_t)col << 6) + quad * 8);
    short8 bfr1 = *(const short8*)(xt + ((size_t)col << 6) + 32 + quad * 8);
    f32x4 c = {};
    c = __builtin_amdgcn_mfma_f32_16x16x32_bf16(afr0, bfr0, c, 0, 0, 0);
    c = __builtin_amdgcn_mfma_f32_16x16x32_bf16(afr1, bfr1, c, 0, 0, 0);
    float sq = sqb[col];
    #pragma unroll
    for (int r = 0; r < 4; ++r)
      dist[quad * 4 + r][col] = sq - 2.f * c[r];
  }
  __syncthreads();
  // phase 2: wave wv selects for row wv; strip col = (l<<6)+lane
  float* dr = dist[wv];
  float v0 = 3e38f, v1 = 3e38f; int i0 = 0x7fffffff, i1 = -1;
  for (int l = 0; l < 32; ++l) {
    int idx = (l << 6) + lane;
    float v = dr[idx];
    if (v < v0) { v1 = v0; i1 = i0; v0 = v; i0 = idx; }
    else if (v < v1) { v1 = v; i1 = idx; }
  }
  for (int pick = 0; pick < 32; ++pick) {
    float bv = v0; int bj = i0;
    #pragma unroll
    for (int off = 32; off > 0; off >>= 1) {
      float ov = __shfl_xor(bv, off);
      int oj = __shfl_xor(bj, off);
      if (ov < bv || (ov == bv && oj < bj)) { bv = ov; bj = oj; }
    }
    if (pick > 0 && lane == 0) cand[wv][pick - 1] = bj;  // pick 0 == self
    if ((bj & 63) == lane) {
      dr[bj] = 3e38f;
      if (i1 >= 0) { v0 = v1; i0 = i1; i1 = -1; v1 = 3e38f; }
      else {
        v0 = 3e38f; v1 = 3e38f; i0 = 0x7fffffff; i1 = -1;
        for (int l = 0; l < 32; ++l) {
          int idx = (l << 6) + lane;
          float v = dr[idx];
          if (v < v0) { v1 = v0; i1 = i0; v0 = v; i0 = idx; }
          else if (v < v1) { v1 = v; i1 = idx; }
        }
      }
    }
  }
  __syncthreads();
  // phase 3: fp64 exact keys for 31 candidates (fp32 source x), rank, emit 20
  const float* xb = x + b * 131072;
  if (lane < 31) {
    int c = cand[wv][lane];
    double dt = 0.0, s2 = 0.0;
    #pragma unroll 8
    for (int d = 0; d < 64; ++d) {
      double vv = (double)xb[d * 2048 + c];
      double ui = (double)xb[d * 2048 + n0 + wv];
      s2 += vv * vv;
      dt += ui * vv;
    }
    dkey[wv][lane] = s2 - 2.0 * dt;
  }
  __syncthreads();
  if (lane < 31) {
    double kl = dkey[wv][lane];
    int ci = cand[wv][lane];
    int rank = 0;
    for (int mm = 0; mm < 31; ++mm) {
      double km = dkey[wv][mm];
      int cm = cand[wv][mm];
      if (km < kl || (km == kl && cm < ci)) ++rank;
    }
    if (rank < 20) idxout[(row0 + wv) * 20 + rank] = ci;
  }
}

// ---------------- conv1 as bf16 MFMA (tap decomposition, xT staging) ----------------
// Block: 16 points x 128 channels (4 waves x 2 col-tiles of 16ch). 21 slices
// staged once from xbf_t as contiguous 128-B columns; main loop barrier-free.
__global__ __launch_bounds__(256) void conv1_mfma(
    const ushort* __restrict__ xbf_t, const int* __restrict__ idxbuf,
    const ushort* __restrict__ wp1, uint* __restrict__ hu) {
  __shared__ ushort sl[21][16][72];   // 48384 B; rows 144 B (16-B aligned)
  __shared__ int nidx[16][20];
  int tid = threadIdx.x;
  int pg = blockIdx.x >> 1;
  int cg = blockIdx.x & 1;
  int p0 = pg << 4;
  int b = p0 >> 11, n0 = p0 & 2047;
  const ushort* xt = xbf_t + ((size_t)b << 17);
  for (int v = tid; v < 320; v += 256) {
    int p = v / 20, j = v - p * 20;
    nidx[p][j] = idxbuf[(p0 + p) * 20 + j];
  }
  __syncthreads();
  // 21 slices x 16 points x 8 chunks of short8
  for (int v = tid; v < 2688; v += 256) {
    int s = v >> 7;
    int r = v & 127;
    int p = r >> 3, i = r & 7;
    int col = (s == 0) ? (n0 + p) : nidx[p][s - 1];
    *(short8*)&sl[s][p][i << 3] =
        *(const short8*)(xt + ((size_t)col << 6) + (i << 3));
  }
  __syncthreads();
  int lane = tid & 63, wave = tid >> 6;
  int m = lane & 15, quad = lane >> 4;
  int ch0 = (cg << 7) + (wave << 4) + m;    // + ct*64
  f32x4 acc[10][2] = {};
  f32x4 cacc[2] = {};
  {
    short8 a0 = *(const short8*)&sl[0][m][quad * 8];
    short8 a1 = *(const short8*)&sl[0][m][32 + quad * 8];
    #pragma unroll
    for (int ct = 0; ct < 2; ++ct) {
      const ushort* urow = wp1 + 180224 + (ch0 + ct * 64) * 64 + quad * 8;
      short8 b0 = *(const short8*)(urow);
      short8 b1 = *(const short8*)(urow + 32);
      cacc[ct] = __builtin_amdgcn_mfma_f32_16x16x32_bf16(a0, b0, cacc[ct], 0, 0, 0);
      cacc[ct] = __builtin_amdgcn_mfma_f32_16x16x32_bf16(a1, b1, cacc[ct], 0, 0, 0);
    }
  }
  #pragma unroll
  for (int t = 0; t < 11; ++t) {
    short8 b0[2], b1[2];
    #pragma unroll
    for (int ct = 0; ct < 2; ++ct) {
      const ushort* brow = wp1 + t * 16384 + (ch0 + ct * 64) * 64 + quad * 8;
      b0[ct] = *(const short8*)(brow);
      b1[ct] = *(const short8*)(brow + 32);
    }
    #pragma unroll
    for (int ko = 0; ko < 10; ++ko) {
      int s = 1 + ko + t;
      short8 a0 = *(const short8*)&sl[s][m][quad * 8];
      short8 a1 = *(const short8*)&sl[s][m][32 + quad * 8];
      #pragma unroll
      for (int ct = 0; ct < 2; ++ct) {
        acc[ko][ct] = __builtin_amdgcn_mfma_f32_16x16x32_bf16(a0, b0[ct], acc[ko][ct], 0, 0, 0);
        acc[ko][ct] = __builtin_amdgcn_mfma_f32_16x16x32_bf16(a1, b1[ct], acc[ko][ct], 0, 0, 0);
      }
    }
  }
  // epilogue: D layout col=lane&15 -> channel, row=quad*4+r -> point
  #pragma unroll
  for (int ct = 0; ct < 2; ++ct) {
    int c = ch0 + ct * 64;
    #pragma unroll
    for (int r = 0; r < 4; ++r) {
      int p = (quad << 2) + r;
      int base5 = ((p0 + p) * 256 + c) * 5;
      float cc = cacc[ct][r];
      #pragma unroll
      for (int q = 0; q < 5; ++q) {
        float f0 = acc[2 * q][ct][r] + cc;
        float f1 = acc[2 * q + 1][ct][r] + cc;
        hu[base5 + q] = f2bf(f0) | (f2bf(f1) << 16);
      }
    }
  }
}

// ---------------- BN stats ----------------
__global__ __launch_bounds__(256) void stats1_kernel(const uint* __restrict__ hu,
                                                     float* __restrict__ stats) {
  int c = threadIdx.x;
  float s = 0.f, ss = 0.f;
  for (int row = blockIdx.x; row < 16384; row += 1024) {
    int base = (row * 256 + c) * 5;
    #pragma unroll
    for (int q = 0; q < 5; ++q) {
      uint v = hu[base + q];
      float f0 = bf2f(v & 0xffffu), f1 = bf2f(v >> 16);
      s += f0 + f1; ss += f0 * f0 + f1 * f1;
    }
  }
  atomicAdd(&stats[c], s);
  atomicAdd(&stats[256 + c], ss);
}

__global__ void finalize_kernel(const float* __restrict__ stats,
                                const float* __restrict__ gamma,
                                const float* __restrict__ beta,
                                float* __restrict__ coef, float inv_count) {
  int c = threadIdx.x;
  float m = stats[c] * inv_count;
  float var = stats[256 + c] * inv_count - m * m;
  float a = gamma[c] * rsqrtf(var + 1e-5f);
  coef[c] = a;
  coef[256 + c] = beta[c] - m * a;
}

// ---------------- conv2 as bf16 MFMA GEMM (xT staging) ----------------
__global__ __launch_bounds__(256) void conv2_mfma(
    const ushort* __restrict__ xbf_t, const int* __restrict__ idxbuf,
    const uint* __restrict__ hu, const float* __restrict__ coef1,
    const ushort* __restrict__ wpack, float* __restrict__ yraw) {
  __shared__ ushort As[2][32][72];
  __shared__ int nidx[32][20];
  __shared__ float cf[512];
  int tid = threadIdx.x;
  int p0 = blockIdx.x << 5;          // 32 points per block
  int b = p0 >> 11, n0 = p0 & 2047;
  const ushort* xt = xbf_t + ((size_t)b << 17);

  cf[tid] = coef1[tid];
  cf[256 + tid] = coef1[256 + tid];
  for (int v = tid; v < 640; v += 256) {
    int p = v / 20, j = v - p * 20;
    nidx[p][j] = idxbuf[(p0 + p) * 20 + j];
  }
  __syncthreads();

  auto build = [&](int kb, int buf) {
    if (kb < 21) {
      // one column (central or neighbor kb-1) per point, contiguous in xT
      int p = tid >> 3, i = tid & 7;
      int col = (kb == 0) ? (n0 + p) : nidx[p][kb - 1];
      *(short8*)&As[buf][p][i << 3] =
          *(const short8*)(xt + ((size_t)col << 6) + (i << 3));
    } else {
      int p = tid >> 3;
      int off = (tid & 7) << 3;
      int q0 = (kb - 21) * 64 + off;
      const uint* hp = hu + (size_t)(p0 + p) * 1280 + (q0 >> 1);
      uint4 hv = *(const uint4*)hp;
      float f[8];
      f[0] = bf2f(hv.x & 0xffffu); f[1] = bf2f(hv.x >> 16);
      f[2] = bf2f(hv.y & 0xffffu); f[3] = bf2f(hv.y >> 16);
      f[4] = bf2f(hv.z & 0xffffu); f[5] = bf2f(hv.z >> 16);
      f[6] = bf2f(hv.w & 0xffffu); f[7] = bf2f(hv.w >> 16);
      ushort o[8];
      #pragma unroll
      for (int i = 0; i < 8; ++i) {
        int ch = (q0 + i) / 10;
        float vv = f[i] * cf[ch] + cf[256 + ch];
        vv = vv > 0.f ? vv : 0.01f * vv;
        o[i] = (ushort)f2bf(vv);
      }
      *(short8*)&As[buf][p][off] = *(short8*)o;
    }
  };

  int lane = tid & 63, wave = tid >> 6;
  int m = lane & 15, quad = lane >> 4;
  int n0w = wave << 6;
  f32x4 acc[2][4] = {};

  build(0, 0);
  __syncthreads();
  for (int kb = 0; kb < 61; ++kb) {
    int buf = kb & 1;
    if (kb < 60) build(kb + 1, buf ^ 1);
    #pragma unroll
    for (int ks = 0; ks < 2; ++ks) {
      short8 afr0 = *(const short8*)&As[buf][m][ks * 32 + quad * 8];
      short8 afr1 = *(const short8*)&As[buf][16 + m][ks * 32 + quad * 8];
      #pragma unroll
      for (int nt = 0; nt < 4; ++nt) {
        const ushort* bp = wpack + (((size_t)kb << 14) |
                                    (uint)((n0w + nt * 16 + m) << 6) |
                                    (uint)(ks * 32 + quad * 8));
        short8 bfr = *(const short8*)bp;
        acc[0][nt] = __builtin_amdgcn_mfma_f32_16x16x32_bf16(afr0, bfr, acc[0][nt], 0, 0, 0);
        acc[1][nt] = __builtin_amdgcn_mfma_f32_16x16x32_bf16(afr1, bfr, acc[1][nt], 0, 0, 0);
      }
    }
    __syncthreads();
  }
  #pragma unroll
  for (int mt = 0; mt < 2; ++mt) {
    #pragma unroll
    for (int nt = 0; nt < 4; ++nt) {
      int col = n0w + nt * 16 + m;
      #pragma unroll
      for (int r = 0; r < 4; ++r) {
        int prow = mt * 16 + quad * 4 + r;
        yraw[(size_t)(p0 + prow) * 256 + col] = acc[mt][nt][r];
      }
    }
  }
}

__global__ __launch_bounds__(256) void stats2_kernel(const float* __restrict__ yraw,
                                                     float* __restrict__ stats) {
  int c = threadIdx.x;
  float s = 0.f, ss = 0.f;
  for (int row = blockIdx.x; row < 16384; row += 1024) {
    float v = yraw[row * 256 + c];
    s += v; ss += v * v;
  }
  atomicAdd(&stats[c], s);
  atomicAdd(&stats[256 + c], ss);
}

// ---------------- BN2 + relu + transpose to (b, c, n) ----------------
__global__ __launch_bounds__(256) void out_kernel(const float* __restrict__ yraw,
                                                  const float* __restrict__ coef2,
                                                  float* __restrict__ out) {
  __shared__ float t[64][257];
  int tid = threadIdx.x;
  int blk = blockIdx.x;            // 256 = 8 b x 32 n-tiles
  int b = blk >> 5, n0 = (blk & 31) << 6;
  for (int it = 0; it < 64; ++it)
    t[it][tid] = yraw[(b * 2048 + n0 + it) * 256 + tid];
  __syncthreads();
  int nsub = tid & 63, cq = tid >> 6;
  for (int it = 0; it < 64; ++it) {
    int c = (it << 2) + cq;
    float v = coef2[c] * t[nsub][c] + coef2[256 + c];
    out[(b * 256 + c) * 2048 + n0 + nsub] = v > 0.f ? v : 0.f;
  }
}

extern "C" void kernel_launch(void* const* d_in, const int* in_sizes, int n_in,
                              void* d_out, int out_size, void* d_ws, size_t ws_size,
                              hipStream_t stream) {
  const float* x   = (const float*)d_in[0];
  const float* w1  = (const float*)d_in[1];
  const float* g1  = (const float*)d_in[3];
  const float* be1 = (const float*)d_in[4];
  const float* w2  = (const float*)d_in[5];
  const float* g2  = (const float*)d_in[7];
  const float* be2 = (const float*)d_in[8];
  float* out = (float*)d_out;
  char* w = (char*)d_ws;
  // workspace layout (~106.6 MB total)
  float* sqf    = (float*)(w);                 // 16384 * 4 (slot 131072 B)
  int*  idxbuf  = (int*)(w + 131072);          // 327680 * 4     = 1310720
  uint* hu      = (uint*)(w + 1441792);        // h bf16: 83886080 B
  float* yraw   = (float*)(w + 85327872);      // 4194304 * 4    = 16777216
  float* stats  = (float*)(w + 102105088);     // 4 * 256 floats
  float* coef   = (float*)(w + 102109184);     // 4 * 256 floats
  ushort* wp1   = (ushort*)(w + 102113280);    // 196608 * 2 = 393216
  ushort* wpack = (ushort*)(w + 102506496);    // 999424 * 2 = 1998848
  ushort* xbf_t = (ushort*)(w + 104505344);    // 1048576 * 2 -> end 106602496

  hipMemsetAsync(stats, 0, 4096, stream);
  prep_weights<<<4672, 256, 0, stream>>>(w1, w2, wp1, wpack);
  transpose_x<<<256, 256, 0, stream>>>(x, (uint*)xbf_t);
  sqnorm_kernel<<<64, 256, 0, stream>>>(x, sqf);
  knn_kernel<<<1024, 1024, 0, stream>>>(x, xbf_t, sqf, idxbuf);
  conv1_mfma<<<2048, 256, 0, stream>>>(xbf_t, idxbuf, wp1, hu);
  stats1_kernel<<<1024, 256, 0, stream>>>(hu, stats);
  finalize_kernel<<<1, 256, 0, stream>>>(stats, g1, be1, coef, 1.f / 163840.f);
  conv2_mfma<<<512, 256, 0, stream>>>(xbf_t, idxbuf, hu, coef, wpack, yraw);
  stats2_kernel<<<1024, 256, 0, stream>>>(yraw, stats + 512);
  finalize_kernel<<<1, 256, 0, stream>>>(stats + 512, g2, be2, coef + 512, 1.f / 16384.f);
  out_kernel<<<256, 256, 0, stream>>>(yraw, coef + 512, out);
}

// Round 9
// 522.436 us; speedup vs baseline: 7.6562x; 1.3231x over previous
//
#include <hip/hip_runtime.h>
#include <stdint.h>

typedef unsigned int uint;
typedef unsigned short ushort;
typedef __attribute__((ext_vector_type(8))) short short8;
typedef __attribute__((ext_vector_type(4))) float f32x4;

__device__ __forceinline__ uint f2bf(float f) {
  uint u = __float_as_uint(f);
  return (u + 0x7fffu + ((u >> 16) & 1u)) >> 16;
}
__device__ __forceinline__ float bf2f(uint us) {
  return __uint_as_float(us << 16);
}

// ---------------- weight preprocessing ----------------
// w1: (256, 128, 1, 11)  w2: (256, 128, 1, 40)
// wp1 (bf16): [t(11)][c(256)][d(64)] = w1[c][64+d][t]; then U block at
//   180224 + c*64 + d = sum_t (w1[c][d][t] - w1[c][64+d][t])
// wpack (bf16): conv2 GEMM B, layout [kb(61)][c(256)][kk(64)]; K order:
//   k<64:        U2[d=k][c]
//   64<=k<1344:  j-major neighbor: j=(k-64)>>6, d=(k-64)&63 -> w2[c][64+d][j]
//   1344<=k<3904: interleave: q=k-1344=ci*20+jj -> w2[c][ci][20+jj]
__global__ __launch_bounds__(256) void prep_weights(
    const float* __restrict__ w1, const float* __restrict__ w2,
    ushort* __restrict__ wp1, ushort* __restrict__ wpack) {
  int g = blockIdx.x * 256 + threadIdx.x;
  if (g < 180224) {
    int t = g >> 14;
    int r = g & 16383;
    int c = r >> 6, d = r & 63;
    wp1[g] = (ushort)f2bf(w1[c * 1408 + (64 + d) * 11 + t]);
  } else if (g < 196608) {
    int q = g - 180224;
    int c = q >> 6, d = q & 63;
    float s = 0.f;
    for (int t = 0; t < 11; ++t)
      s += w1[c * 1408 + d * 11 + t] - w1[c * 1408 + (64 + d) * 11 + t];
    wp1[g] = (ushort)f2bf(s);
  } else {
    int gp = g - 196608;            // < 999424 = 61*16384
    int kb = gp >> 14;
    int r = gp & 16383;
    int c = r >> 6, kk = r & 63;
    int k = kb * 64 + kk;
    float val;
    if (k < 64) {
      int d = k;
      float s = 0.f;
      for (int j = 0; j < 20; ++j)
        s += w2[c * 5120 + d * 40 + j] - w2[c * 5120 + (64 + d) * 40 + j];
      val = s;
    } else if (k < 1344) {
      int q = k - 64; int j = q >> 6, d = q & 63;
      val = w2[c * 5120 + (64 + d) * 40 + j];
    } else {
      int q = k - 1344; int ci = q / 20, jj = q - ci * 20;
      val = w2[c * 5120 + ci * 40 + 20 + jj];
    }
    wpack[gp] = (ushort)f2bf(val);
  }
}

// ---------------- x transpose: bf16 [b][n][d] + fp32 [b][n][d] ----------------
__global__ __launch_bounds__(256) void transpose_x(const float* __restrict__ x,
                                                   uint* __restrict__ xtu,
                                                   float* __restrict__ xtf) {
  __shared__ float t[64][65];
  int tid = threadIdx.x;
  int blk = blockIdx.x;            // 256 = 8 b x 32 n-tiles
  int b = blk >> 5, n0 = (blk & 31) << 6;
  const float* xb = x + b * 131072;
  #pragma unroll
  for (int it = 0; it < 16; ++it) {
    int d = (it << 2) + (tid >> 6);
    int n = tid & 63;
    t[d][n] = xb[d * 2048 + n0 + n];
  }
  __syncthreads();
  #pragma unroll
  for (int it = 0; it < 8; ++it) {
    int n = (it << 3) + (tid >> 5);
    int dp = tid & 31;
    float f0 = t[2 * dp][n], f1 = t[2 * dp + 1][n];
    uint v = f2bf(f0) | (f2bf(f1) << 16);
    size_t col = (size_t)(b * 2048 + n0 + n);
    xtu[col * 32 + dp] = v;
    float2 fv; fv.x = f0; fv.y = f1;
    *(float2*)&xtf[(col << 6) + 2 * dp] = fv;
  }
}

// ---------------- squared norms (fp32, for the pre-selection only) ----------------
__global__ __launch_bounds__(256) void sqnorm_kernel(const float* __restrict__ x,
                                                     float* __restrict__ sqf) {
  int g = blockIdx.x * 256 + threadIdx.x;  // 16384
  int b = g >> 11, n = g & 2047;
  const float* xp = x + b * 131072 + n;
  float s = 0.f;
  #pragma unroll
  for (int d = 0; d < 64; ++d) { float v = xp[d * 2048]; s += v * v; }
  sqf[g] = s;
}

// ---------------- kNN v6: MFMA dists -> packed-u32 keys, min-only tournament,
// ---------------- fp64 exact re-rank of the top-31 superset ----------------
// key = (sortable_fp32 & ~0x7FF) | col : u32-min == (dist, col) lexicographic
// at 2^-12 granularity. Self killed up front; 31 picks; per-lane top-4 in
// registers (rescan ~never). Phase 3 re-ranks the 31 candidates with exact
// fp64 keys from fp32 data (contiguous xtf columns).
__global__ __launch_bounds__(1024) void knn_kernel(
    const float* __restrict__ xtf, const ushort* __restrict__ xbf_t,
    const float* __restrict__ sqf, int* __restrict__ idxout) {
  __shared__ uint dist[16][2048];   // 128 KB packed keys
  __shared__ int cand[16][31];
  __shared__ double dkey[16][31];
  int tid = threadIdx.x;
  int wv = tid >> 6, lane = tid & 63;
  int row0 = blockIdx.x << 4;
  int b = row0 >> 11, n0 = row0 & 2047;
  const ushort* xt = xbf_t + ((size_t)b << 17);
  const float* sqb = sqf + (b << 11);
  int m = lane & 15, quad = lane >> 4;
  short8 afr0 = *(const short8*)(xt + ((size_t)(n0 + m) << 6) + quad * 8);
  short8 afr1 = *(const short8*)(xt + ((size_t)(n0 + m) << 6) + 32 + quad * 8);
  // phase 1: wave wv computes col-tiles [wv*8, wv*8+8); writes packed keys
  for (int t = 0; t < 8; ++t) {
    int col = (((wv << 3) + t) << 4) + m;
    short8 bfr0 = *(const short8*)(xt + ((size_t)col << 6) + quad * 8);
    short8 bfr1 = *(const short8*)(xt + ((size_t)col << 6) + 32 + quad * 8);
    f32x4 c = {};
    c = __builtin_amdgcn_mfma_f32_16x16x32_bf16(afr0, bfr0, c, 0, 0, 0);
    c = __builtin_amdgcn_mfma_f32_16x16x32_bf16(afr1, bfr1, c, 0, 0, 0);
    float sq = sqb[col];
    #pragma unroll
    for (int r = 0; r < 4; ++r) {
      float f = sq - 2.f * c[r];
      uint u = __float_as_uint(f);
      uint srt = u ^ ((uint)((int)u >> 31) | 0x80000000u);
      dist[quad * 4 + r][col] = (srt & 0xFFFFF800u) | (uint)col;
    }
  }
  __syncthreads();
  uint* dr = dist[wv];
  int selfcol = n0 + wv;
  if ((selfcol & 63) == lane) dr[selfcol] = 0xFFFFFFFFu;  // kill self (own strip)
  // per-lane sorted top-4 over strip col = (l<<6)+lane
  uint v0, v1, v2, v3;
  auto scan4 = [&]() {
    v0 = v1 = v2 = v3 = 0xFFFFFFFFu;
    #pragma unroll
    for (int l = 0; l < 32; ++l) {
      uint v = dr[(l << 6) + lane];
      uint t0 = v0 > v ? v0 : v;   v0 = v0 < v ? v0 : v;
      uint t1 = v1 > t0 ? v1 : t0; v1 = v1 < t0 ? v1 : t0;
      uint t2 = v2 > t1 ? v2 : t1; v2 = v2 < t1 ? v2 : t1;
      v3 = v3 < t2 ? v3 : t2;
    }
  };
  scan4();
  for (int pick = 0; pick < 31; ++pick) {
    uint bv = v0;
    #pragma unroll
    for (int off = 32; off > 0; off >>= 1) {
      uint ov = (uint)__shfl_xor((int)bv, off);
      bv = bv < ov ? bv : ov;
    }
    int bj = (int)(bv & 2047u);
    if (lane == 0) cand[wv][pick] = bj;
    if ((bj & 63) == lane) {
      dr[bj] = 0xFFFFFFFFu;
      v0 = v1; v1 = v2; v2 = v3; v3 = 0xFFFFFFFFu;
      if (v0 == 0xFFFFFFFFu) scan4();   // ~never (4th win of one lane)
    }
  }
  __syncthreads();
  // phase 3: exact fp64 keys from fp32 xtf (contiguous 256-B columns)
  const float* xc = xtf + ((size_t)b << 17);
  const float4* xi4 = (const float4*)(xc + ((size_t)selfcol << 6));
  if (lane < 31) {
    int c = cand[wv][lane];
    const float4* xj4 = (const float4*)(xc + ((size_t)c << 6));
    double dt = 0.0, s2 = 0.0;
    #pragma unroll 4
    for (int d4 = 0; d4 < 16; ++d4) {
      float4 vj = xj4[d4];
      float4 vi = xi4[d4];
      double a0 = (double)vj.x, a1 = (double)vj.y, a2 = (double)vj.z, a3 = (double)vj.w;
      s2 += a0 * a0 + a1 * a1 + a2 * a2 + a3 * a3;
      dt += (double)vi.x * a0 + (double)vi.y * a1 + (double)vi.z * a2 + (double)vi.w * a3;
    }
    dkey[wv][lane] = s2 - 2.0 * dt;
  }
  __syncthreads();
  if (lane < 31) {
    double kl = dkey[wv][lane];
    int ci = cand[wv][lane];
    int rank = 0;
    for (int mm = 0; mm < 31; ++mm) {
      double km = dkey[wv][mm];
      int cm = cand[wv][mm];
      if (km < kl || (km == kl && cm < ci)) ++rank;
    }
    if (rank < 20) idxout[(row0 + wv) * 20 + rank] = ci;
  }
}

// ---------------- conv1 as bf16 MFMA (tap decomposition, xT staging) ----------------
// Block: 16 points x 128 channels (4 waves x 2 col-tiles of 16ch). 21 slices
// staged once from xbf_t as contiguous 128-B columns; main loop barrier-free.
__global__ __launch_bounds__(256) void conv1_mfma(
    const ushort* __restrict__ xbf_t, const int* __restrict__ idxbuf,
    const ushort* __restrict__ wp1, uint* __restrict__ hu) {
  __shared__ ushort sl[21][16][72];   // 48384 B; rows 144 B (16-B aligned)
  __shared__ int nidx[16][20];
  int tid = threadIdx.x;
  int pg = blockIdx.x >> 1;
  int cg = blockIdx.x & 1;
  int p0 = pg << 4;
  int b = p0 >> 11, n0 = p0 & 2047;
  const ushort* xt = xbf_t + ((size_t)b << 17);
  for (int v = tid; v < 320; v += 256) {
    int p = v / 20, j = v - p * 20;
    nidx[p][j] = idxbuf[(p0 + p) * 20 + j];
  }
  __syncthreads();
  // 21 slices x 16 points x 8 chunks of short8
  for (int v = tid; v < 2688; v += 256) {
    int s = v >> 7;
    int r = v & 127;
    int p = r >> 3, i = r & 7;
    int col = (s == 0) ? (n0 + p) : nidx[p][s - 1];
    *(short8*)&sl[s][p][i << 3] =
        *(const short8*)(xt + ((size_t)col << 6) + (i << 3));
  }
  __syncthreads();
  int lane = tid & 63, wave = tid >> 6;
  int m = lane & 15, quad = lane >> 4;
  int ch0 = (cg << 7) + (wave << 4) + m;    // + ct*64
  f32x4 acc[10][2] = {};
  f32x4 cacc[2] = {};
  {
    short8 a0 = *(const short8*)&sl[0][m][quad * 8];
    short8 a1 = *(const short8*)&sl[0][m][32 + quad * 8];
    #pragma unroll
    for (int ct = 0; ct < 2; ++ct) {
      const ushort* urow = wp1 + 180224 + (ch0 + ct * 64) * 64 + quad * 8;
      short8 b0 = *(const short8*)(urow);
      short8 b1 = *(const short8*)(urow + 32);
      cacc[ct] = __builtin_amdgcn_mfma_f32_16x16x32_bf16(a0, b0, cacc[ct], 0, 0, 0);
      cacc[ct] = __builtin_amdgcn_mfma_f32_16x16x32_bf16(a1, b1, cacc[ct], 0, 0, 0);
    }
  }
  #pragma unroll
  for (int t = 0; t < 11; ++t) {
    short8 b0[2], b1[2];
    #pragma unroll
    for (int ct = 0; ct < 2; ++ct) {
      const ushort* brow = wp1 + t * 16384 + (ch0 + ct * 64) * 64 + quad * 8;
      b0[ct] = *(const short8*)(brow);
      b1[ct] = *(const short8*)(brow + 32);
    }
    #pragma unroll
    for (int ko = 0; ko < 10; ++ko) {
      int s = 1 + ko + t;
      short8 a0 = *(const short8*)&sl[s][m][quad * 8];
      short8 a1 = *(const short8*)&sl[s][m][32 + quad * 8];
      #pragma unroll
      for (int ct = 0; ct < 2; ++ct) {
        acc[ko][ct] = __builtin_amdgcn_mfma_f32_16x16x32_bf16(a0, b0[ct], acc[ko][ct], 0, 0, 0);
        acc[ko][ct] = __builtin_amdgcn_mfma_f32_16x16x32_bf16(a1, b1[ct], acc[ko][ct], 0, 0, 0);
      }
    }
  }
  // epilogue: D layout col=lane&15 -> channel, row=quad*4+r -> point
  #pragma unroll
  for (int ct = 0; ct < 2; ++ct) {
    int c = ch0 + ct * 64;
    #pragma unroll
    for (int r = 0; r < 4; ++r) {
      int p = (quad << 2) + r;
      int base5 = ((p0 + p) * 256 + c) * 5;
      float cc = cacc[ct][r];
      #pragma unroll
      for (int q = 0; q < 5; ++q) {
        float f0 = acc[2 * q][ct][r] + cc;
        float f1 = acc[2 * q + 1][ct][r] + cc;
        hu[base5 + q] = f2bf(f0) | (f2bf(f1) << 16);
      }
    }
  }
}

// ---------------- BN stats ----------------
__global__ __launch_bounds__(256) void stats1_kernel(const uint* __restrict__ hu,
                                                     float* __restrict__ stats) {
  int c = threadIdx.x;
  float s = 0.f, ss = 0.f;
  for (int row = blockIdx.x; row < 16384; row += 1024) {
    int base = (row * 256 + c) * 5;
    #pragma unroll
    for (int q = 0; q < 5; ++q) {
      uint v = hu[base + q];
      float f0 = bf2f(v & 0xffffu), f1 = bf2f(v >> 16);
      s += f0 + f1; ss += f0 * f0 + f1 * f1;
    }
  }
  atomicAdd(&stats[c], s);
  atomicAdd(&stats[256 + c], ss);
}

__global__ void finalize_kernel(const float* __restrict__ stats,
                                const float* __restrict__ gamma,
                                const float* __restrict__ beta,
                                float* __restrict__ coef, float inv_count) {
  int c = threadIdx.x;
  float m = stats[c] * inv_count;
  float var = stats[256 + c] * inv_count - m * m;
  float a = gamma[c] * rsqrtf(var + 1e-5f);
  coef[c] = a;
  coef[256 + c] = beta[c] - m * a;
}

// ---------------- conv2 as bf16 MFMA GEMM (xT staging) ----------------
__global__ __launch_bounds__(256) void conv2_mfma(
    const ushort* __restrict__ xbf_t, const int* __restrict__ idxbuf,
    const uint* __restrict__ hu, const float* __restrict__ coef1,
    const ushort* __restrict__ wpack, float* __restrict__ yraw) {
  __shared__ ushort As[2][32][72];
  __shared__ int nidx[32][20];
  __shared__ float cf[512];
  int tid = threadIdx.x;
  int p0 = blockIdx.x << 5;          // 32 points per block
  int b = p0 >> 11, n0 = p0 & 2047;
  const ushort* xt = xbf_t + ((size_t)b << 17);

  cf[tid] = coef1[tid];
  cf[256 + tid] = coef1[256 + tid];
  for (int v = tid; v < 640; v += 256) {
    int p = v / 20, j = v - p * 20;
    nidx[p][j] = idxbuf[(p0 + p) * 20 + j];
  }
  __syncthreads();

  auto build = [&](int kb, int buf) {
    if (kb < 21) {
      // one column (central or neighbor kb-1) per point, contiguous in xT
      int p = tid >> 3, i = tid & 7;
      int col = (kb == 0) ? (n0 + p) : nidx[p][kb - 1];
      *(short8*)&As[buf][p][i << 3] =
          *(const short8*)(xt + ((size_t)col << 6) + (i << 3));
    } else {
      int p = tid >> 3;
      int off = (tid & 7) << 3;
      int q0 = (kb - 21) * 64 + off;
      const uint* hp = hu + (size_t)(p0 + p) * 1280 + (q0 >> 1);
      uint4 hv = *(const uint4*)hp;
      float f[8];
      f[0] = bf2f(hv.x & 0xffffu); f[1] = bf2f(hv.x >> 16);
      f[2] = bf2f(hv.y & 0xffffu); f[3] = bf2f(hv.y >> 16);
      f[4] = bf2f(hv.z & 0xffffu); f[5] = bf2f(hv.z >> 16);
      f[6] = bf2f(hv.w & 0xffffu); f[7] = bf2f(hv.w >> 16);
      ushort o[8];
      #pragma unroll
      for (int i = 0; i < 8; ++i) {
        int ch = (q0 + i) / 10;
        float vv = f[i] * cf[ch] + cf[256 + ch];
        vv = vv > 0.f ? vv : 0.01f * vv;
        o[i] = (ushort)f2bf(vv);
      }
      *(short8*)&As[buf][p][off] = *(short8*)o;
    }
  };

  int lane = tid & 63, wave = tid >> 6;
  int m = lane & 15, quad = lane >> 4;
  int n0w = wave << 6;
  f32x4 acc[2][4] = {};

  build(0, 0);
  __syncthreads();
  for (int kb = 0; kb < 61; ++kb) {
    int buf = kb & 1;
    if (kb < 60) build(kb + 1, buf ^ 1);
    #pragma unroll
    for (int ks = 0; ks < 2; ++ks) {
      short8 afr0 = *(const short8*)&As[buf][m][ks * 32 + quad * 8];
      short8 afr1 = *(const short8*)&As[buf][16 + m][ks * 32 + quad * 8];
      #pragma unroll
      for (int nt = 0; nt < 4; ++nt) {
        const ushort* bp = wpack + (((size_t)kb << 14) |
                                    (uint)((n0w + nt * 16 + m) << 6) |
                                    (uint)(ks * 32 + quad * 8));
        short8 bfr = *(const short8*)bp;
        acc[0][nt] = __builtin_amdgcn_mfma_f32_16x16x32_bf16(afr0, bfr, acc[0][nt], 0, 0, 0);
        acc[1][nt] = __builtin_amdgcn_mfma_f32_16x16x32_bf16(afr1, bfr, acc[1][nt], 0, 0, 0);
      }
    }
    __syncthreads();
  }
  #pragma unroll
  for (int mt = 0; mt < 2; ++mt) {
    #pragma unroll
    for (int nt = 0; nt < 4; ++nt) {
      int col = n0w + nt * 16 + m;
      #pragma unroll
      for (int r = 0; r < 4; ++r) {
        int prow = mt * 16 + quad * 4 + r;
        yraw[(size_t)(p0 + prow) * 256 + col] = acc[mt][nt][r];
      }
    }
  }
}

__global__ __launch_bounds__(256) void stats2_kernel(const float* __restrict__ yraw,
                                                     float* __restrict__ stats) {
  int c = threadIdx.x;
  float s = 0.f, ss = 0.f;
  for (int row = blockIdx.x; row < 16384; row += 1024) {
    float v = yraw[row * 256 + c];
    s += v; ss += v * v;
  }
  atomicAdd(&stats[c], s);
  atomicAdd(&stats[256 + c], ss);
}

// ---------------- BN2 + relu + transpose to (b, c, n) ----------------
__global__ __launch_bounds__(256) void out_kernel(const float* __restrict__ yraw,
                                                  const float* __restrict__ coef2,
                                                  float* __restrict__ out) {
  __shared__ float t[64][257];
  int tid = threadIdx.x;
  int blk = blockIdx.x;            // 256 = 8 b x 32 n-tiles
  int b = blk >> 5, n0 = (blk & 31) << 6;
  for (int it = 0; it < 64; ++it)
    t[it][tid] = yraw[(b * 2048 + n0 + it) * 256 + tid];
  __syncthreads();
  int nsub = tid & 63, cq = tid >> 6;
  for (int it = 0; it < 64; ++it) {
    int c = (it << 2) + cq;
    float v = coef2[c] * t[nsub][c] + coef2[256 + c];
    out[(b * 256 + c) * 2048 + n0 + nsub] = v > 0.f ? v : 0.f;
  }
}

extern "C" void kernel_launch(void* const* d_in, const int* in_sizes, int n_in,
                              void* d_out, int out_size, void* d_ws, size_t ws_size,
                              hipStream_t stream) {
  const float* x   = (const float*)d_in[0];
  const float* w1  = (const float*)d_in[1];
  const float* g1  = (const float*)d_in[3];
  const float* be1 = (const float*)d_in[4];
  const float* w2  = (const float*)d_in[5];
  const float* g2  = (const float*)d_in[7];
  const float* be2 = (const float*)d_in[8];
  float* out = (float*)d_out;
  char* w = (char*)d_ws;
  // workspace layout (~106.6 MB total)
  float* sqf    = (float*)(w);                 // 16384 * 4 (slot 131072 B)
  int*  idxbuf  = (int*)(w + 131072);          // 327680 * 4     = 1310720
  uint* hu      = (uint*)(w + 1441792);        // h bf16: 83886080 B
  float* xtf    = (float*)(w + 1441792);       // fp32 xT, 8 MB — ALIASES hu:
                                               // used only in knn (before conv1)
  float* yraw   = (float*)(w + 85327872);      // 4194304 * 4    = 16777216
  float* stats  = (float*)(w + 102105088);     // 4 * 256 floats
  float* coef   = (float*)(w + 102109184);     // 4 * 256 floats
  ushort* wp1   = (ushort*)(w + 102113280);    // 196608 * 2 = 393216
  ushort* wpack = (ushort*)(w + 102506496);    // 999424 * 2 = 1998848
  ushort* xbf_t = (ushort*)(w + 104505344);    // 1048576 * 2 -> end 106602496

  hipMemsetAsync(stats, 0, 4096, stream);
  prep_weights<<<4672, 256, 0, stream>>>(w1, w2, wp1, wpack);
  transpose_x<<<256, 256, 0, stream>>>(x, (uint*)xbf_t, xtf);
  sqnorm_kernel<<<64, 256, 0, stream>>>(x, sqf);
  knn_kernel<<<1024, 1024, 0, stream>>>(xtf, xbf_t, sqf, idxbuf);
  conv1_mfma<<<2048, 256, 0, stream>>>(xbf_t, idxbuf, wp1, hu);
  stats1_kernel<<<1024, 256, 0, stream>>>(hu, stats);
  finalize_kernel<<<1, 256, 0, stream>>>(stats, g1, be1, coef, 1.f / 163840.f);
  conv2_mfma<<<512, 256, 0, stream>>>(xbf_t, idxbuf, hu, coef, wpack, yraw);
  stats2_kernel<<<1024, 256, 0, stream>>>(yraw, stats + 512);
  finalize_kernel<<<1, 256, 0, stream>>>(stats + 512, g2, be2, coef + 512, 1.f / 16384.f);
  out_kernel<<<256, 256, 0, stream>>>(yraw, coef + 512, out);
}

// Round 10
// 516.974 us; speedup vs baseline: 7.7371x; 1.0106x over previous
//
#include <hip/hip_runtime.h>
#include <stdint.h>

typedef unsigned int uint;
typedef unsigned short ushort;
typedef __attribute__((ext_vector_type(8))) short short8;
typedef __attribute__((ext_vector_type(4))) float f32x4;

__device__ __forceinline__ uint f2bf(float f) {
  uint u = __float_as_uint(f);
  return (u + 0x7fffu + ((u >> 16) & 1u)) >> 16;
}
__device__ __forceinline__ float bf2f(uint us) {
  return __uint_as_float(us << 16);
}

// ---------------- weight preprocessing ----------------
// w1: (256, 128, 1, 11)  w2: (256, 128, 1, 40)
// wp1 (bf16): [t(11)][c(256)][d(64)] = w1[c][64+d][t]; then U block at
//   180224 + c*64 + d = sum_t (w1[c][d][t] - w1[c][64+d][t])
// wpack (bf16): conv2 GEMM B, layout [kb(61)][c(256)][kk(64)]; K order:
//   k<64:        U2[d=k][c]
//   64<=k<1344:  j-major neighbor: j=(k-64)>>6, d=(k-64)&63 -> w2[c][64+d][j]
//   1344<=k<3904: interleave: q=k-1344=ci*20+jj -> w2[c][ci][20+jj]
__global__ __launch_bounds__(256) void prep_weights(
    const float* __restrict__ w1, const float* __restrict__ w2,
    ushort* __restrict__ wp1, ushort* __restrict__ wpack) {
  int g = blockIdx.x * 256 + threadIdx.x;
  if (g < 180224) {
    int t = g >> 14;
    int r = g & 16383;
    int c = r >> 6, d = r & 63;
    wp1[g] = (ushort)f2bf(w1[c * 1408 + (64 + d) * 11 + t]);
  } else if (g < 196608) {
    int q = g - 180224;
    int c = q >> 6, d = q & 63;
    float s = 0.f;
    for (int t = 0; t < 11; ++t)
      s += w1[c * 1408 + d * 11 + t] - w1[c * 1408 + (64 + d) * 11 + t];
    wp1[g] = (ushort)f2bf(s);
  } else {
    int gp = g - 196608;            // < 999424 = 61*16384
    int kb = gp >> 14;
    int r = gp & 16383;
    int c = r >> 6, kk = r & 63;
    int k = kb * 64 + kk;
    float val;
    if (k < 64) {
      int d = k;
      float s = 0.f;
      for (int j = 0; j < 20; ++j)
        s += w2[c * 5120 + d * 40 + j] - w2[c * 5120 + (64 + d) * 40 + j];
      val = s;
    } else if (k < 1344) {
      int q = k - 64; int j = q >> 6, d = q & 63;
      val = w2[c * 5120 + (64 + d) * 40 + j];
    } else {
      int q = k - 1344; int ci = q / 20, jj = q - ci * 20;
      val = w2[c * 5120 + ci * 40 + 20 + jj];
    }
    wpack[gp] = (ushort)f2bf(val);
  }
}

// ---------------- x transpose: bf16 [b][n][d] + fp32 [b][n][d] ----------------
__global__ __launch_bounds__(256) void transpose_x(const float* __restrict__ x,
                                                   uint* __restrict__ xtu,
                                                   float* __restrict__ xtf) {
  __shared__ float t[64][65];
  int tid = threadIdx.x;
  int blk = blockIdx.x;            // 256 = 8 b x 32 n-tiles
  int b = blk >> 5, n0 = (blk & 31) << 6;
  const float* xb = x + b * 131072;
  #pragma unroll
  for (int it = 0; it < 16; ++it) {
    int d = (it << 2) + (tid >> 6);
    int n = tid & 63;
    t[d][n] = xb[d * 2048 + n0 + n];
  }
  __syncthreads();
  #pragma unroll
  for (int it = 0; it < 8; ++it) {
    int n = (it << 3) + (tid >> 5);
    int dp = tid & 31;
    float f0 = t[2 * dp][n], f1 = t[2 * dp + 1][n];
    uint v = f2bf(f0) | (f2bf(f1) << 16);
    size_t col = (size_t)(b * 2048 + n0 + n);
    xtu[col * 32 + dp] = v;
    float2 fv; fv.x = f0; fv.y = f1;
    *(float2*)&xtf[(col << 6) + 2 * dp] = fv;
  }
}

// ---------------- squared norms (fp32, for the pre-selection only) ----------------
__global__ __launch_bounds__(256) void sqnorm_kernel(const float* __restrict__ x,
                                                     float* __restrict__ sqf) {
  int g = blockIdx.x * 256 + threadIdx.x;  // 16384
  int b = g >> 11, n = g & 2047;
  const float* xp = x + b * 131072 + n;
  float s = 0.f;
  #pragma unroll
  for (int d = 0; d < 64; ++d) { float v = xp[d * 2048]; s += v * v; }
  sqf[g] = s;
}

// ---------------- kNN v6: MFMA dists -> packed-u32 keys, min-only tournament,
// ---------------- fp64 exact re-rank of the top-31 superset ----------------
__global__ __launch_bounds__(1024) void knn_kernel(
    const float* __restrict__ xtf, const ushort* __restrict__ xbf_t,
    const float* __restrict__ sqf, int* __restrict__ idxout) {
  __shared__ uint dist[16][2048];   // 128 KB packed keys
  __shared__ int cand[16][31];
  __shared__ double dkey[16][31];
  int tid = threadIdx.x;
  int wv = tid >> 6, lane = tid & 63;
  int row0 = blockIdx.x << 4;
  int b = row0 >> 11, n0 = row0 & 2047;
  const ushort* xt = xbf_t + ((size_t)b << 17);
  const float* sqb = sqf + (b << 11);
  int m = lane & 15, quad = lane >> 4;
  short8 afr0 = *(const short8*)(xt + ((size_t)(n0 + m) << 6) + quad * 8);
  short8 afr1 = *(const short8*)(xt + ((size_t)(n0 + m) << 6) + 32 + quad * 8);
  // phase 1: wave wv computes col-tiles [wv*8, wv*8+8); writes packed keys
  for (int t = 0; t < 8; ++t) {
    int col = (((wv << 3) + t) << 4) + m;
    short8 bfr0 = *(const short8*)(xt + ((size_t)col << 6) + quad * 8);
    short8 bfr1 = *(const short8*)(xt + ((size_t)col << 6) + 32 + quad * 8);
    f32x4 c = {};
    c = __builtin_amdgcn_mfma_f32_16x16x32_bf16(afr0, bfr0, c, 0, 0, 0);
    c = __builtin_amdgcn_mfma_f32_16x16x32_bf16(afr1, bfr1, c, 0, 0, 0);
    float sq = sqb[col];
    #pragma unroll
    for (int r = 0; r < 4; ++r) {
      float f = sq - 2.f * c[r];
      uint u = __float_as_uint(f);
      uint srt = u ^ ((uint)((int)u >> 31) | 0x80000000u);
      dist[quad * 4 + r][col] = (srt & 0xFFFFF800u) | (uint)col;
    }
  }
  __syncthreads();
  uint* dr = dist[wv];
  int selfcol = n0 + wv;
  if ((selfcol & 63) == lane) dr[selfcol] = 0xFFFFFFFFu;  // kill self (own strip)
  // per-lane sorted top-4 over strip col = (l<<6)+lane
  uint v0, v1, v2, v3;
  auto scan4 = [&]() {
    v0 = v1 = v2 = v3 = 0xFFFFFFFFu;
    #pragma unroll
    for (int l = 0; l < 32; ++l) {
      uint v = dr[(l << 6) + lane];
      uint t0 = v0 > v ? v0 : v;   v0 = v0 < v ? v0 : v;
      uint t1 = v1 > t0 ? v1 : t0; v1 = v1 < t0 ? v1 : t0;
      uint t2 = v2 > t1 ? v2 : t1; v2 = v2 < t1 ? v2 : t1;
      v3 = v3 < t2 ? v3 : t2;
    }
  };
  scan4();
  for (int pick = 0; pick < 31; ++pick) {
    uint bv = v0;
    #pragma unroll
    for (int off = 32; off > 0; off >>= 1) {
      uint ov = (uint)__shfl_xor((int)bv, off);
      bv = bv < ov ? bv : ov;
    }
    int bj = (int)(bv & 2047u);
    if (lane == 0) cand[wv][pick] = bj;
    if ((bj & 63) == lane) {
      dr[bj] = 0xFFFFFFFFu;
      v0 = v1; v1 = v2; v2 = v3; v3 = 0xFFFFFFFFu;
      if (v0 == 0xFFFFFFFFu) scan4();   // ~never (4th win of one lane)
    }
  }
  __syncthreads();
  // phase 3: exact fp64 keys from fp32 xtf (contiguous 256-B columns)
  const float* xc = xtf + ((size_t)b << 17);
  const float4* xi4 = (const float4*)(xc + ((size_t)selfcol << 6));
  if (lane < 31) {
    int c = cand[wv][lane];
    const float4* xj4 = (const float4*)(xc + ((size_t)c << 6));
    double dt = 0.0, s2 = 0.0;
    #pragma unroll 4
    for (int d4 = 0; d4 < 16; ++d4) {
      float4 vj = xj4[d4];
      float4 vi = xi4[d4];
      double a0 = (double)vj.x, a1 = (double)vj.y, a2 = (double)vj.z, a3 = (double)vj.w;
      s2 += a0 * a0 + a1 * a1 + a2 * a2 + a3 * a3;
      dt += (double)vi.x * a0 + (double)vi.y * a1 + (double)vi.z * a2 + (double)vi.w * a3;
    }
    dkey[wv][lane] = s2 - 2.0 * dt;
  }
  __syncthreads();
  if (lane < 31) {
    double kl = dkey[wv][lane];
    int ci = cand[wv][lane];
    int rank = 0;
    for (int mm = 0; mm < 31; ++mm) {
      double km = dkey[wv][mm];
      int cm = cand[wv][mm];
      if (km < kl || (km == kl && cm < ci)) ++rank;
    }
    if (rank < 20) idxout[(row0 + wv) * 20 + rank] = ci;
  }
}

// ---------------- conv1 as bf16 MFMA (tap decomposition, xT staging) ----------------
__global__ __launch_bounds__(256) void conv1_mfma(
    const ushort* __restrict__ xbf_t, const int* __restrict__ idxbuf,
    const ushort* __restrict__ wp1, uint* __restrict__ hu) {
  __shared__ ushort sl[21][16][72];   // 48384 B; rows 144 B (16-B aligned)
  __shared__ int nidx[16][20];
  int tid = threadIdx.x;
  int pg = blockIdx.x >> 1;
  int cg = blockIdx.x & 1;
  int p0 = pg << 4;
  int b = p0 >> 11, n0 = p0 & 2047;
  const ushort* xt = xbf_t + ((size_t)b << 17);
  for (int v = tid; v < 320; v += 256) {
    int p = v / 20, j = v - p * 20;
    nidx[p][j] = idxbuf[(p0 + p) * 20 + j];
  }
  __syncthreads();
  // 21 slices x 16 points x 8 chunks of short8
  for (int v = tid; v < 2688; v += 256) {
    int s = v >> 7;
    int r = v & 127;
    int p = r >> 3, i = r & 7;
    int col = (s == 0) ? (n0 + p) : nidx[p][s - 1];
    *(short8*)&sl[s][p][i << 3] =
        *(const short8*)(xt + ((size_t)col << 6) + (i << 3));
  }
  __syncthreads();
  int lane = tid & 63, wave = tid >> 6;
  int m = lane & 15, quad = lane >> 4;
  int ch0 = (cg << 7) + (wave << 4) + m;    // + ct*64
  f32x4 acc[10][2] = {};
  f32x4 cacc[2] = {};
  {
    short8 a0 = *(const short8*)&sl[0][m][quad * 8];
    short8 a1 = *(const short8*)&sl[0][m][32 + quad * 8];
    #pragma unroll
    for (int ct = 0; ct < 2; ++ct) {
      const ushort* urow = wp1 + 180224 + (ch0 + ct * 64) * 64 + quad * 8;
      short8 b0 = *(const short8*)(urow);
      short8 b1 = *(const short8*)(urow + 32);
      cacc[ct] = __builtin_amdgcn_mfma_f32_16x16x32_bf16(a0, b0, cacc[ct], 0, 0, 0);
      cacc[ct] = __builtin_amdgcn_mfma_f32_16x16x32_bf16(a1, b1, cacc[ct], 0, 0, 0);
    }
  }
  #pragma unroll
  for (int t = 0; t < 11; ++t) {
    short8 b0[2], b1[2];
    #pragma unroll
    for (int ct = 0; ct < 2; ++ct) {
      const ushort* brow = wp1 + t * 16384 + (ch0 + ct * 64) * 64 + quad * 8;
      b0[ct] = *(const short8*)(brow);
      b1[ct] = *(const short8*)(brow + 32);
    }
    #pragma unroll
    for (int ko = 0; ko < 10; ++ko) {
      int s = 1 + ko + t;
      short8 a0 = *(const short8*)&sl[s][m][quad * 8];
      short8 a1 = *(const short8*)&sl[s][m][32 + quad * 8];
      #pragma unroll
      for (int ct = 0; ct < 2; ++ct) {
        acc[ko][ct] = __builtin_amdgcn_mfma_f32_16x16x32_bf16(a0, b0[ct], acc[ko][ct], 0, 0, 0);
        acc[ko][ct] = __builtin_amdgcn_mfma_f32_16x16x32_bf16(a1, b1[ct], acc[ko][ct], 0, 0, 0);
      }
    }
  }
  // epilogue: D layout col=lane&15 -> channel, row=quad*4+r -> point
  #pragma unroll
  for (int ct = 0; ct < 2; ++ct) {
    int c = ch0 + ct * 64;
    #pragma unroll
    for (int r = 0; r < 4; ++r) {
      int p = (quad << 2) + r;
      int base5 = ((p0 + p) * 256 + c) * 5;
      float cc = cacc[ct][r];
      #pragma unroll
      for (int q = 0; q < 5; ++q) {
        float f0 = acc[2 * q][ct][r] + cc;
        float f1 = acc[2 * q + 1][ct][r] + cc;
        hu[base5 + q] = f2bf(f0) | (f2bf(f1) << 16);
      }
    }
  }
}

// ---------------- BN stats ----------------
__global__ __launch_bounds__(256) void stats1_kernel(const uint* __restrict__ hu,
                                                     float* __restrict__ stats) {
  int c = threadIdx.x;
  float s = 0.f, ss = 0.f;
  for (int row = blockIdx.x; row < 16384; row += 1024) {
    int base = (row * 256 + c) * 5;
    #pragma unroll
    for (int q = 0; q < 5; ++q) {
      uint v = hu[base + q];
      float f0 = bf2f(v & 0xffffu), f1 = bf2f(v >> 16);
      s += f0 + f1; ss += f0 * f0 + f1 * f1;
    }
  }
  atomicAdd(&stats[c], s);
  atomicAdd(&stats[256 + c], ss);
}

__global__ void finalize_kernel(const float* __restrict__ stats,
                                const float* __restrict__ gamma,
                                const float* __restrict__ beta,
                                float* __restrict__ coef, float inv_count) {
  int c = threadIdx.x;
  float m = stats[c] * inv_count;
  float var = stats[256 + c] * inv_count - m * m;
  float a = gamma[c] * rsqrtf(var + 1e-5f);
  coef[c] = a;
  coef[256 + c] = beta[c] - m * a;
}

// ---------------- conv2 as bf16 MFMA GEMM (xT staging, channel-split) ----------------
// Block: 32 points x 128 channels (cg in {0,1}); grid 1024 -> 4 blocks/CU for
// latency overlap of the hu stream. Each wave: 2 m-tiles x 2 nt-tiles (32 ch).
__global__ __launch_bounds__(256) void conv2_mfma(
    const ushort* __restrict__ xbf_t, const int* __restrict__ idxbuf,
    const uint* __restrict__ hu, const float* __restrict__ coef1,
    const ushort* __restrict__ wpack, float* __restrict__ yraw) {
  __shared__ ushort As[2][32][72];
  __shared__ int nidx[32][20];
  __shared__ float cf[512];
  int tid = threadIdx.x;
  int pg = blockIdx.x >> 1;
  int cg = blockIdx.x & 1;
  int p0 = pg << 5;                  // 32 points per block
  int b = p0 >> 11, n0 = p0 & 2047;
  const ushort* xt = xbf_t + ((size_t)b << 17);

  cf[tid] = coef1[tid];
  cf[256 + tid] = coef1[256 + tid];
  for (int v = tid; v < 640; v += 256) {
    int p = v / 20, j = v - p * 20;
    nidx[p][j] = idxbuf[(p0 + p) * 20 + j];
  }
  __syncthreads();

  auto build = [&](int kb, int buf) {
    if (kb < 21) {
      // one column (central or neighbor kb-1) per point, contiguous in xT
      int p = tid >> 3, i = tid & 7;
      int col = (kb == 0) ? (n0 + p) : nidx[p][kb - 1];
      *(short8*)&As[buf][p][i << 3] =
          *(const short8*)(xt + ((size_t)col << 6) + (i << 3));
    } else {
      int p = tid >> 3;
      int off = (tid & 7) << 3;
      int q0 = (kb - 21) * 64 + off;
      const uint* hp = hu + (size_t)(p0 + p) * 1280 + (q0 >> 1);
      uint4 hv = *(const uint4*)hp;
      float f[8];
      f[0] = bf2f(hv.x & 0xffffu); f[1] = bf2f(hv.x >> 16);
      f[2] = bf2f(hv.y & 0xffffu); f[3] = bf2f(hv.y >> 16);
      f[4] = bf2f(hv.z & 0xffffu); f[5] = bf2f(hv.z >> 16);
      f[6] = bf2f(hv.w & 0xffffu); f[7] = bf2f(hv.w >> 16);
      ushort o[8];
      #pragma unroll
      for (int i = 0; i < 8; ++i) {
        int ch = (q0 + i) / 10;
        float vv = f[i] * cf[ch] + cf[256 + ch];
        vv = vv > 0.f ? vv : 0.01f * vv;
        o[i] = (ushort)f2bf(vv);
      }
      *(short8*)&As[buf][p][off] = *(short8*)o;
    }
  };

  int lane = tid & 63, wave = tid >> 6;
  int m = lane & 15, quad = lane >> 4;
  int n0w = (cg << 7) + (wave << 5);   // 32-ch slice per wave
  f32x4 acc[2][2] = {};

  build(0, 0);
  __syncthreads();
  for (int kb = 0; kb < 61; ++kb) {
    int buf = kb & 1;
    if (kb < 60) build(kb + 1, buf ^ 1);
    #pragma unroll
    for (int ks = 0; ks < 2; ++ks) {
      short8 afr0 = *(const short8*)&As[buf][m][ks * 32 + quad * 8];
      short8 afr1 = *(const short8*)&As[buf][16 + m][ks * 32 + quad * 8];
      #pragma unroll
      for (int nt = 0; nt < 2; ++nt) {
        const ushort* bp = wpack + (((size_t)kb << 14) |
                                    (uint)((n0w + nt * 16 + m) << 6) |
                                    (uint)(ks * 32 + quad * 8));
        short8 bfr = *(const short8*)bp;
        acc[0][nt] = __builtin_amdgcn_mfma_f32_16x16x32_bf16(afr0, bfr, acc[0][nt], 0, 0, 0);
        acc[1][nt] = __builtin_amdgcn_mfma_f32_16x16x32_bf16(afr1, bfr, acc[1][nt], 0, 0, 0);
      }
    }
    __syncthreads();
  }
  #pragma unroll
  for (int mt = 0; mt < 2; ++mt) {
    #pragma unroll
    for (int nt = 0; nt < 2; ++nt) {
      int col = n0w + nt * 16 + m;
      #pragma unroll
      for (int r = 0; r < 4; ++r) {
        int prow = mt * 16 + quad * 4 + r;
        yraw[(size_t)(p0 + prow) * 256 + col] = acc[mt][nt][r];
      }
    }
  }
}

__global__ __launch_bounds__(256) void stats2_kernel(const float* __restrict__ yraw,
                                                     float* __restrict__ stats) {
  int c = threadIdx.x;
  float s = 0.f, ss = 0.f;
  for (int row = blockIdx.x; row < 16384; row += 1024) {
    float v = yraw[row * 256 + c];
    s += v; ss += v * v;
  }
  atomicAdd(&stats[c], s);
  atomicAdd(&stats[256 + c], ss);
}

// ---------------- BN2 + relu + transpose to (b, c, n) ----------------
__global__ __launch_bounds__(256) void out_kernel(const float* __restrict__ yraw,
                                                  const float* __restrict__ coef2,
                                                  float* __restrict__ out) {
  __shared__ float t[64][257];
  int tid = threadIdx.x;
  int blk = blockIdx.x;            // 256 = 8 b x 32 n-tiles
  int b = blk >> 5, n0 = (blk & 31) << 6;
  for (int it = 0; it < 64; ++it)
    t[it][tid] = yraw[(b * 2048 + n0 + it) * 256 + tid];
  __syncthreads();
  int nsub = tid & 63, cq = tid >> 6;
  for (int it = 0; it < 64; ++it) {
    int c = (it << 2) + cq;
    float v = coef2[c] * t[nsub][c] + coef2[256 + c];
    out[(b * 256 + c) * 2048 + n0 + nsub] = v > 0.f ? v : 0.f;
  }
}

extern "C" void kernel_launch(void* const* d_in, const int* in_sizes, int n_in,
                              void* d_out, int out_size, void* d_ws, size_t ws_size,
                              hipStream_t stream) {
  const float* x   = (const float*)d_in[0];
  const float* w1  = (const float*)d_in[1];
  const float* g1  = (const float*)d_in[3];
  const float* be1 = (const float*)d_in[4];
  const float* w2  = (const float*)d_in[5];
  const float* g2  = (const float*)d_in[7];
  const float* be2 = (const float*)d_in[8];
  float* out = (float*)d_out;
  char* w = (char*)d_ws;
  // workspace layout (~106.6 MB total)
  float* sqf    = (float*)(w);                 // 16384 * 4 (slot 131072 B)
  int*  idxbuf  = (int*)(w + 131072);          // 327680 * 4     = 1310720
  uint* hu      = (uint*)(w + 1441792);        // h bf16: 83886080 B
  float* xtf    = (float*)(w + 1441792);       // fp32 xT, 8 MB — ALIASES hu:
                                               // used only in knn (before conv1)
  float* yraw   = (float*)(w + 85327872);      // 4194304 * 4    = 16777216
  float* stats  = (float*)(w + 102105088);     // 4 * 256 floats
  float* coef   = (float*)(w + 102109184);     // 4 * 256 floats
  ushort* wp1   = (ushort*)(w + 102113280);    // 196608 * 2 = 393216
  ushort* wpack = (ushort*)(w + 102506496);    // 999424 * 2 = 1998848
  ushort* xbf_t = (ushort*)(w + 104505344);    // 1048576 * 2 -> end 106602496

  hipMemsetAsync(stats, 0, 4096, stream);
  prep_weights<<<4672, 256, 0, stream>>>(w1, w2, wp1, wpack);
  transpose_x<<<256, 256, 0, stream>>>(x, (uint*)xbf_t, xtf);
  sqnorm_kernel<<<64, 256, 0, stream>>>(x, sqf);
  knn_kernel<<<1024, 1024, 0, stream>>>(xtf, xbf_t, sqf, idxbuf);
  conv1_mfma<<<2048, 256, 0, stream>>>(xbf_t, idxbuf, wp1, hu);
  stats1_kernel<<<1024, 256, 0, stream>>>(hu, stats);
  finalize_kernel<<<1, 256, 0, stream>>>(stats, g1, be1, coef, 1.f / 163840.f);
  conv2_mfma<<<1024, 256, 0, stream>>>(xbf_t, idxbuf, hu, coef, wpack, yraw);
  stats2_kernel<<<1024, 256, 0, stream>>>(yraw, stats + 512);
  finalize_kernel<<<1, 256, 0, stream>>>(stats + 512, g2, be2, coef + 512, 1.f / 16384.f);
  out_kernel<<<256, 256, 0, stream>>>(yraw, coef + 512, out);
}